// Round 1
// baseline (1660.875 us; speedup 1.0000x reference)
//
#include <hip/hip_runtime.h>
#include <hip/hip_bf16.h>

// DCell forward, fp32. 5 sequential stages; per stage:
//   1) gemm_stage:    h[b,t,o] = sum_i inp[b,t,i] * W[t,i,o] + bias[t,o]
//                     inp gathered from (act_prev reshaped | gene block of x)
//   2) bn_stats:      per-(t,o) sum and sumsq over batch (atomic chunk reduce)
//   3) bn_final:      mu, rsqrt(var+eps)
//   4) bn_tanh_head:  act = tanh((h-mu)*rsig*g+bb) in-place; head[b,t] = act.hw + hb
//
// Stage cfg (T, I, O, C=act channels, Gs=genes/term):
//  s4:(256,16,20,0,16) s3:(64,144,20,80,64) s2:(16,336,77,80,256)
//  s1:(4,1332,308,308,1024) s0:(1,5328,1229,1232,4096)
// Output row = 341 = 256+64+16+4+1, head offsets 0,256,320,336,340.

#define BDIM 2048
#define OUTW 341

#define BM 64
#define BN 64
#define BK 16

__global__ __launch_bounds__(256) void gemm_stage(
    const float* __restrict__ x,     // B x 4096
    const float* __restrict__ actp,  // B x (T*C) or null
    const float* __restrict__ W,     // T x I x O
    const float* __restrict__ bias,  // T x O
    float* __restrict__ h,           // B x T x O
    int T, int I, int O, int C, int Gs)
{
    const int t  = blockIdx.z;
    const int b0 = blockIdx.y * BM;
    const int o0 = blockIdx.x * BN;
    const int tid = threadIdx.x;

    __shared__ float As[BK][BM + 4];
    __shared__ float Bs[BK][BN + 4];

    const int tx = tid & 15;   // col group
    const int ty = tid >> 4;   // row group
    float acc[4][4] = {};

    const float* Wt = W + (size_t)t * I * O;
    const int ka = tid & (BK - 1);   // A load: k index
    const int ma = tid >> 4;         // A load: base row (0..15)
    const int nb = tid & (BN - 1);   // B load: col
    const int kb0 = tid >> 6;        // B load: base k (0..3)

    const size_t act_row = (size_t)T * C;

    for (int k0 = 0; k0 < I; k0 += BK) {
        // A tile: As[k][m] = inp[b0+m, k0+k]
        #pragma unroll
        for (int mm = 0; mm < 4; mm++) {
            int m = ma + mm * 16;
            int i = k0 + ka;
            int b = b0 + m;
            float v = 0.f;
            if (i < I) {
                if (i < C) v = actp[(size_t)b * act_row + (size_t)t * C + i];
                else       v = x[(size_t)b * 4096 + t * Gs + (i - C)];
            }
            As[ka][m] = v;
        }
        // B tile: Bs[k][n] = W[t, k0+k, o0+n]
        #pragma unroll
        for (int kk = 0; kk < 4; kk++) {
            int k = kb0 + kk * 4;
            int i = k0 + k;
            int o = o0 + nb;
            float v = 0.f;
            if (i < I && o < O) v = Wt[(size_t)i * O + o];
            Bs[k][nb] = v;
        }
        __syncthreads();
        #pragma unroll
        for (int k = 0; k < BK; k++) {
            float a[4], bv[4];
            #pragma unroll
            for (int r = 0; r < 4; r++) a[r] = As[k][ty * 4 + r];
            #pragma unroll
            for (int c = 0; c < 4; c++) bv[c] = Bs[k][tx * 4 + c];
            #pragma unroll
            for (int r = 0; r < 4; r++)
                #pragma unroll
                for (int c = 0; c < 4; c++)
                    acc[r][c] += a[r] * bv[c];
        }
        __syncthreads();
    }

    const size_t TO = (size_t)T * O;
    #pragma unroll
    for (int r = 0; r < 4; r++) {
        int b = b0 + ty * 4 + r;
        #pragma unroll
        for (int c = 0; c < 4; c++) {
            int o = o0 + tx * 4 + c;
            if (o < O)
                h[(size_t)b * TO + (size_t)t * O + o] = acc[r][c] + bias[(size_t)t * O + o];
        }
    }
}

// chunked batch reduction: grid.y chunks of 128 rows, atomic accumulate
__global__ __launch_bounds__(256) void bn_stats(
    const float* __restrict__ h, float* __restrict__ acc, int TO)
{
    int col = blockIdx.x * 256 + threadIdx.x;
    if (col >= TO) return;
    const float* p = h + (size_t)blockIdx.y * 128 * TO + col;
    float s = 0.f, s2 = 0.f;
    #pragma unroll 4
    for (int b = 0; b < 128; b++) {
        float v = p[(size_t)b * TO];
        s += v; s2 += v * v;
    }
    atomicAdd(&acc[col], s);
    atomicAdd(&acc[TO + col], s2);
}

__global__ __launch_bounds__(256) void bn_final(float* __restrict__ acc, int TO)
{
    int col = blockIdx.x * 256 + threadIdx.x;
    if (col >= TO) return;
    float s  = acc[col];
    float s2 = acc[TO + col];
    float mu = s * (1.f / BDIM);
    float var = s2 * (1.f / BDIM) - mu * mu;   // biased var, matches jnp.var
    acc[col] = mu;
    acc[TO + col] = rsqrtf(var + 1e-5f);
}

// one wave per (b,t): BN+tanh in place, then head dot product
__global__ __launch_bounds__(256) void bn_tanh_head(
    float* __restrict__ h,              // in: h, out: act (in place)
    const float* __restrict__ stats,    // [TO]=mu, [TO..2TO)=rsig
    const float* __restrict__ g, const float* __restrict__ bb,
    const float* __restrict__ hw, const float* __restrict__ hb,
    float* __restrict__ out, int T, int O, int head_off)
{
    int wid  = (blockIdx.x * 256 + threadIdx.x) >> 6;
    int lane = threadIdx.x & 63;
    int b = wid / T;
    int t = wid % T;
    const int TO = T * O;
    size_t base = (size_t)b * TO + (size_t)t * O;
    float hsum = 0.f;
    for (int o = lane; o < O; o += 64) {
        float v   = h[base + o];
        float mu  = stats[t * O + o];
        float rs  = stats[TO + t * O + o];
        float a   = tanhf((v - mu) * rs * g[t * O + o] + bb[t * O + o]);
        h[base + o] = a;
        hsum += a * hw[t * O + o];
    }
    #pragma unroll
    for (int off = 32; off > 0; off >>= 1) hsum += __shfl_down(hsum, off, 64);
    if (lane == 0) out[(size_t)b * OUTW + head_off + t] = hsum + hb[t];
}

extern "C" void kernel_launch(void* const* d_in, const int* in_sizes, int n_in,
                              void* d_out, int out_size, void* d_ws, size_t ws_size,
                              hipStream_t stream)
{
    const float* x = (const float*)d_in[0];
    float* out = (float*)d_out;

    float* ws   = (float*)d_ws;
    float* buf0 = ws;                       // 10,485,760 floats (stage 4/2/0 h+act)
    float* buf1 = ws + 10485760;            //  2,621,440 floats (stage 3/1 h+act)
    float* stats = ws + 13107200;           //     10,240 floats

    struct Stage { int T, I, O, C, Gs, widx, head_off; };
    const Stage st[5] = {
        {256,   16,   20,    0,   16,  1,   0},
        { 64,  144,   20,   80,   64,  7, 256},
        { 16,  336,   77,   80,  256, 13, 320},
        {  4, 1332,  308,  308, 1024, 19, 336},
        {  1, 5328, 1229, 1232, 4096, 25, 340},
    };
    float* bufs[5] = {buf0, buf1, buf0, buf1, buf0};

    const float* actp = nullptr;
    for (int si = 0; si < 5; si++) {
        const Stage& S = st[si];
        const float* W    = (const float*)d_in[S.widx + 0];
        const float* bias = (const float*)d_in[S.widx + 1];
        const float* g    = (const float*)d_in[S.widx + 2];
        const float* bb   = (const float*)d_in[S.widx + 3];
        const float* hw   = (const float*)d_in[S.widx + 4];
        const float* hb   = (const float*)d_in[S.widx + 5];
        float* h = bufs[si];
        int TO = S.T * S.O;

        dim3 gg((S.O + BN - 1) / BN, BDIM / BM, S.T);
        gemm_stage<<<gg, 256, 0, stream>>>(x, actp, W, bias, h,
                                           S.T, S.I, S.O, S.C, S.Gs);

        hipMemsetAsync(stats, 0, (size_t)TO * 2 * sizeof(float), stream);
        bn_stats<<<dim3((TO + 255) / 256, 16), 256, 0, stream>>>(h, stats, TO);
        bn_final<<<(TO + 255) / 256, 256, 0, stream>>>(stats, TO);
        bn_tanh_head<<<(BDIM * S.T) / 4, 256, 0, stream>>>(
            h, stats, g, bb, hw, hb, out, S.T, S.O, S.head_off);

        actp = h;  // act written in place over h
    }
}

// Round 2
// 674.531 us; speedup vs baseline: 2.4623x; 2.4623x over previous
//
#include <hip/hip_runtime.h>
#include <hip/hip_bf16.h>

// DCell forward, bf16-MFMA path.
// Per stage: cvt_w (fp32 W -> transposed bf16 WbT[t][O][Kpad], K zero-padded)
//            gemm_mfma (A gathered from bf16 act | bf16 x; h bf16 out, fp32 acc)
//            bn_stats/bn_final (fp32 batch stats from bf16 h)
//            bn_tanh_head (act bf16 out + per-term head scalar)
// Stage cfg (T, I, O, C=act chans, Gs): s4(256,16,20,0,16) s3(64,144,20,80,64)
//  s2(16,336,77,80,256) s1(4,1332,308,308,1024) s0(1,5328,1229,1232,4096)

#define BDIM 2048
#define OUTW 341

typedef __attribute__((ext_vector_type(8))) short short8;   // 8 bf16 = 4 VGPRs
typedef __attribute__((ext_vector_type(4))) float float4v;  // MFMA acc

static __device__ __forceinline__ unsigned short f2bf(float f) {
    union { float f; unsigned u; } c{f};
    unsigned r = c.u + 0x7FFF + ((c.u >> 16) & 1);  // RNE
    return (unsigned short)(r >> 16);
}
static __device__ __forceinline__ float bf2f(unsigned short s) {
    union { unsigned u; float f; } c{(unsigned)s << 16};
    return c.f;
}

// ---- x fp32 -> bf16 ----
__global__ __launch_bounds__(256) void cvt_x(const float4* __restrict__ x,
                                             ushort4* __restrict__ xb, int n4) {
    int i = blockIdx.x * 256 + threadIdx.x;
    if (i >= n4) return;
    float4 v = x[i];
    ushort4 o;
    o.x = f2bf(v.x); o.y = f2bf(v.y); o.z = f2bf(v.z); o.w = f2bf(v.w);
    xb[i] = o;
}

// ---- W[t][I][O] fp32 -> WbT[t][O][Kpad] bf16, zero pad k in [I,Kpad) ----
__global__ __launch_bounds__(256) void cvt_w(const float* __restrict__ W,
                                             unsigned short* __restrict__ WbT,
                                             int I, int O, int Kpad) {
    __shared__ unsigned short tile[32][33];
    const int t = blockIdx.z;
    const int i0 = blockIdx.x * 32, o0 = blockIdx.y * 32;
    const int c = threadIdx.x & 31, r0 = threadIdx.x >> 5;  // 32 cols x 8 rows
    const float* Wt = W + (size_t)t * I * O;
    #pragma unroll
    for (int rr = 0; rr < 4; rr++) {
        int i = i0 + r0 + rr * 8, o = o0 + c;
        float v = (i < I && o < O) ? Wt[(size_t)i * O + o] : 0.f;
        tile[r0 + rr * 8][c] = f2bf(v);
    }
    __syncthreads();
    unsigned short* dst = WbT + (size_t)t * O * Kpad;
    #pragma unroll
    for (int rr = 0; rr < 4; rr++) {
        int o = o0 + r0 + rr * 8, k = i0 + c;
        if (o < O) dst[(size_t)o * Kpad + k] = tile[c][r0 + rr * 8];
    }
}

// ---- MFMA GEMM: h[b][t*O+o] = sum_k inp[b,t,k]*W[t,k,o] + bias ----
// inp[b,t,k] = k<C ? act[b][t*C+k] : (k<I ? xb[b][t*Gs+k-C] : 0)
template <int BN, int BK>
__global__ __launch_bounds__(256) void gemm_mfma(
    const unsigned short* __restrict__ actb,  // [B][T*C] bf16 (null if C==0)
    const unsigned short* __restrict__ xb,    // [B][4096] bf16
    const unsigned short* __restrict__ WbT,   // [T][O][Kpad] bf16
    const float* __restrict__ bias,           // [T][O] fp32
    unsigned short* __restrict__ h,           // [B][T*O] bf16
    int T, int I, int O, int C, int Gs, int Kpad)
{
    const int t  = blockIdx.z;
    const int b0 = blockIdx.y * 64;
    const int o0 = blockIdx.x * BN;
    const int tid = threadIdx.x;
    const int lane = tid & 63;
    const int w = tid >> 6;            // 4 waves
    const int l15 = lane & 15;
    const int quad = lane >> 4;

    constexpr int NF = BN / 32;        // n-frags per wave (wave tile 32 x BN/2)
    const int wm = (w & 1) * 32;
    const int wn = (w >> 1) * (BN / 2);

    __shared__ __align__(16) unsigned short As[64][BK + 8];  // [m][k], +8 pad: 2-way banks (free)
    __shared__ __align__(16) unsigned short Bs[BN][BK + 8];  // [n][k]

    float4v acc[2][NF];
    #pragma unroll
    for (int a = 0; a < 2; a++)
        #pragma unroll
        for (int b = 0; b < NF; b++)
            acc[a][b] = (float4v){0.f, 0.f, 0.f, 0.f};

    constexpr int GR = BK / 8;         // 8-elem granules per row
    constexpr int AG = 64 * GR;
    constexpr int BG = BN * GR;
    const size_t actRow = (size_t)T * C;

    for (int k0 = 0; k0 < Kpad; k0 += BK) {
        // A staging: As[r][k] = inp[b0+r, k0+k]
        #pragma unroll
        for (int g = tid; g < AG; g += 256) {
            const int r = g / GR, c8 = g % GR;
            const int k = k0 + c8 * 8;
            const int b = b0 + r;
            uint4 v;
            if (k + 8 <= C) {
                const size_t off = (size_t)b * actRow + (size_t)t * C + k;
                if (((t * C + k) & 7) == 0) {
                    v = *(const uint4*)(actb + off);
                } else {  // 8B-aligned only (s1, odd t)
                    const uint2* p = (const uint2*)(actb + off);
                    uint2 lo = p[0], hi = p[1];
                    v = make_uint4(lo.x, lo.y, hi.x, hi.y);
                }
            } else if (k >= I) {
                v = make_uint4(0u, 0u, 0u, 0u);
            } else if (k >= C && k + 8 <= I) {
                v = *(const uint4*)(xb + (size_t)b * 4096 + (size_t)t * Gs + (k - C));
            } else {  // straddles C or I boundary (rare)
                union { unsigned short u[8]; uint4 v; } tmp;
                #pragma unroll
                for (int j = 0; j < 8; j++) {
                    int kk = k + j;
                    unsigned short e = 0;
                    if (kk < C)       e = actb[(size_t)b * actRow + (size_t)t * C + kk];
                    else if (kk < I)  e = xb[(size_t)b * 4096 + (size_t)t * Gs + (kk - C)];
                    tmp.u[j] = e;
                }
                v = tmp.v;
            }
            *(uint4*)&As[r][c8 * 8] = v;
        }
        // B staging: Bs[n][k] = W[t, k0+k, o0+n] (from transposed WbT)
        #pragma unroll
        for (int g = tid; g < BG; g += 256) {
            const int n = g / GR, c8 = g % GR;
            const int o = o0 + n;
            uint4 v = make_uint4(0u, 0u, 0u, 0u);
            if (o < O)
                v = *(const uint4*)(WbT + ((size_t)t * O + o) * Kpad + k0 + c8 * 8);
            *(uint4*)&Bs[n][c8 * 8] = v;
        }
        __syncthreads();
        #pragma unroll
        for (int ks = 0; ks < BK / 32; ks++) {
            const int koff = ks * 32 + quad * 8;
            short8 a0 = *(const short8*)&As[wm + l15][koff];
            short8 a1 = *(const short8*)&As[wm + 16 + l15][koff];
            #pragma unroll
            for (int fn = 0; fn < NF; fn++) {
                short8 bf = *(const short8*)&Bs[wn + fn * 16 + l15][koff];
                acc[0][fn] = __builtin_amdgcn_mfma_f32_16x16x32_bf16(a0, bf, acc[0][fn], 0, 0, 0);
                acc[1][fn] = __builtin_amdgcn_mfma_f32_16x16x32_bf16(a1, bf, acc[1][fn], 0, 0, 0);
            }
        }
        __syncthreads();
    }

    // epilogue: D row=(quad*4+r) (m), col=l15 (n)  [m89-verified mapping]
    const size_t TO = (size_t)T * O;
    #pragma unroll
    for (int fm = 0; fm < 2; fm++)
        #pragma unroll
        for (int fn = 0; fn < NF; fn++)
            #pragma unroll
            for (int r = 0; r < 4; r++) {
                int m = wm + fm * 16 + quad * 4 + r;
                int o = o0 + wn + fn * 16 + l15;
                if (o < O) {
                    float v = acc[fm][fn][r] + bias[t * O + o];
                    h[(size_t)(b0 + m) * TO + (size_t)t * O + o] = f2bf(v);
                }
            }
}

// ---- BN batch stats: chunked atomic reduce over B ----
__global__ __launch_bounds__(256) void bn_stats(const unsigned short* __restrict__ h,
                                                float* __restrict__ acc, int TO) {
    int col = blockIdx.x * 256 + threadIdx.x;
    if (col >= TO) return;
    const unsigned short* p = h + (size_t)blockIdx.y * 128 * TO + col;
    float s = 0.f, s2 = 0.f;
    #pragma unroll 4
    for (int b = 0; b < 128; b++) {
        float v = bf2f(p[(size_t)b * TO]);
        s += v; s2 += v * v;
    }
    atomicAdd(&acc[col], s);
    atomicAdd(&acc[TO + col], s2);
}

__global__ __launch_bounds__(256) void bn_final(float* __restrict__ acc, int TO) {
    int col = blockIdx.x * 256 + threadIdx.x;
    if (col >= TO) return;
    float mu = acc[col] * (1.f / BDIM);
    float var = acc[TO + col] * (1.f / BDIM) - mu * mu;  // biased, matches jnp.var
    acc[col] = mu;
    acc[TO + col] = rsqrtf(var + 1e-5f);
}

// ---- BN + tanh + head: one wave per (b,t) ----
__global__ __launch_bounds__(256) void bn_tanh_head(
    const unsigned short* __restrict__ h, const float* __restrict__ stats,
    const float* __restrict__ g, const float* __restrict__ bb,
    const float* __restrict__ hw, const float* __restrict__ hb,
    unsigned short* __restrict__ actOut, float* __restrict__ out,
    int T, int O, int head_off)
{
    int wid  = (blockIdx.x * 256 + threadIdx.x) >> 6;
    int lane = threadIdx.x & 63;
    int b = wid / T;
    int t = wid % T;
    const int TO = T * O;
    size_t base = (size_t)b * TO + (size_t)t * O;
    float hsum = 0.f;
    for (int o = lane; o < O; o += 64) {
        float v = bf2f(h[base + o]);
        float a = tanhf((v - stats[t * O + o]) * stats[TO + t * O + o] * g[t * O + o]
                        + bb[t * O + o]);
        actOut[base + o] = f2bf(a);
        hsum += a * hw[t * O + o];
    }
    #pragma unroll
    for (int off = 32; off > 0; off >>= 1) hsum += __shfl_down(hsum, off, 64);
    if (lane == 0) out[(size_t)b * OUTW + head_off + t] = hsum + hb[t];
}

extern "C" void kernel_launch(void* const* d_in, const int* in_sizes, int n_in,
                              void* d_out, int out_size, void* d_ws, size_t ws_size,
                              hipStream_t stream)
{
    const float* x = (const float*)d_in[0];
    float* out = (float*)d_out;
    char* ws = (char*)d_ws;

    // ws layout (bytes, 256-aligned); total ~77.2 MB
    unsigned short* xb    = (unsigned short*)(ws + 0);           // 2048*4096*2 = 16,777,216
    unsigned short* wbt   = (unsigned short*)(ws + 16777216);    // max 1229*5376*2 = 13,214,208
    unsigned short* hbuf  = (unsigned short*)(ws + 29991424);    // 2048*5120*2 = 20,971,520
    unsigned short* actA  = (unsigned short*)(ws + 50962944);    // 20,971,520
    unsigned short* actB  = (unsigned short*)(ws + 71934464);    //  5,242,880
    float*          stats = (float*)(ws + 77177344);             //     40,960

    cvt_x<<<(BDIM * 4096 / 4 + 255) / 256, 256, 0, stream>>>((const float4*)x,
                                                             (ushort4*)xb, BDIM * 4096 / 4);

    struct StageCfg { int T, I, O, C, Gs, Kpad, BN, BK, widx, head_off; };
    const StageCfg st[5] = {
        {256,   16,   20,    0,   16,   32, 32, 32,  1,   0},
        { 64,  144,   20,   80,   64,  192, 32, 64,  7, 256},
        { 16,  336,   77,   80,  256,  384, 64, 64, 13, 320},
        {  4, 1332,  308,  308, 1024, 1344, 64, 64, 19, 336},
        {  1, 5328, 1229, 1232, 4096, 5376, 64, 64, 25, 340},
    };
    unsigned short* actOut[5] = {actA, actB, actA, actB, actA};

    const unsigned short* actPrev = nullptr;
    for (int si = 0; si < 5; si++) {
        const StageCfg& S = st[si];
        const float* W    = (const float*)d_in[S.widx + 0];
        const float* bias = (const float*)d_in[S.widx + 1];
        const float* g    = (const float*)d_in[S.widx + 2];
        const float* bb   = (const float*)d_in[S.widx + 3];
        const float* hw   = (const float*)d_in[S.widx + 4];
        const float* hb   = (const float*)d_in[S.widx + 5];
        const int TO = S.T * S.O;

        cvt_w<<<dim3(S.Kpad / 32, (S.O + 31) / 32, S.T), 256, 0, stream>>>(W, wbt, S.I, S.O, S.Kpad);

        dim3 gg((S.O + S.BN - 1) / S.BN, BDIM / 64, S.T);
        if (S.BN == 64)
            gemm_mfma<64, 64><<<gg, 256, 0, stream>>>(actPrev, xb, wbt, bias, hbuf,
                                                      S.T, S.I, S.O, S.C, S.Gs, S.Kpad);
        else if (S.BK == 64)
            gemm_mfma<32, 64><<<gg, 256, 0, stream>>>(actPrev, xb, wbt, bias, hbuf,
                                                      S.T, S.I, S.O, S.C, S.Gs, S.Kpad);
        else
            gemm_mfma<32, 32><<<gg, 256, 0, stream>>>(actPrev, xb, wbt, bias, hbuf,
                                                      S.T, S.I, S.O, S.C, S.Gs, S.Kpad);

        hipMemsetAsync(stats, 0, (size_t)TO * 2 * sizeof(float), stream);
        bn_stats<<<dim3((TO + 255) / 256, 16), 256, 0, stream>>>(hbuf, stats, TO);
        bn_final<<<(TO + 255) / 256, 256, 0, stream>>>(stats, TO);
        bn_tanh_head<<<(BDIM * S.T) / 4, 256, 0, stream>>>(hbuf, stats, g, bb, hw, hb,
                                                           actOut[si], out, S.T, S.O, S.head_off);
        actPrev = actOut[si];
    }
}

// Round 3
// 617.091 us; speedup vs baseline: 2.6915x; 1.0931x over previous
//
#include <hip/hip_runtime.h>
#include <hip/hip_bf16.h>

// DCell forward, bf16-MFMA, m97-style split-K GEMM for the two big stages.
// Stages (T, I, O, C=act chans, Gs): s4(256,16,20,0,16) s3(64,144,20,80,64)
//  s2(16,336,77,80,256) s1(4,1332,308,308,1024) s0(1,5328,1229,1232,4096)
// s4/s3/s2: gemm_small (VGPR staging; tiny GEMMs, many blocks).
// s1/s0: inputs pre-packed to contiguous zero-padded bf16 rows (Ain1/Ain0);
//        gemm_split: 128-row tiles, BK=32, global_load_lds(16B) staging into
//        XOR-swizzled LDS, split-K fp32 partials + reduce.
// BN per stage fused: memset+bn_stats (atomic chunk sums) + bn_tanh_head
// (computes mu/rsig inline, writes act [optionally strided into Ain] + head).

#define BDIM 2048
#define OUTW 341

typedef __attribute__((ext_vector_type(8))) short short8;   // 8 bf16 = 4 VGPRs
typedef __attribute__((ext_vector_type(4))) float float4v;  // MFMA acc

static __device__ __forceinline__ unsigned short f2bf(float f) {
    union { float f; unsigned u; } c{f};
    unsigned r = c.u + 0x7FFF + ((c.u >> 16) & 1);  // RNE
    return (unsigned short)(r >> 16);
}
static __device__ __forceinline__ float bf2f(unsigned short s) {
    union { unsigned u; float f; } c{(unsigned)s << 16};
    return c.f;
}

// async global->LDS, 16B/lane. LDS dest semantics: wave-uniform base + lane*16.
static __device__ __forceinline__ void stage16(const void* g, void* ldsBase, int lane) {
#if __has_builtin(__builtin_amdgcn_global_load_lds)
    __builtin_amdgcn_global_load_lds(
        (const __attribute__((address_space(1))) unsigned int*)(uintptr_t)g,
        (__attribute__((address_space(3))) unsigned int*)(unsigned int)(uintptr_t)ldsBase,
        16, 0, 0);
#else
    *(uint4*)((char*)ldsBase + lane * 16) = *(const uint4*)g;
#endif
}

// ---- pack x (fp32) -> Ain0[b][5376]: cols [1232,5328)=x genes, [5328,5376)=0
__global__ __launch_bounds__(256) void pack_ain0(const float* __restrict__ x,
                                                 unsigned short* __restrict__ ain0) {
    const int GPR = 518;  // 16B granules per row
    int i = blockIdx.x * 256 + threadIdx.x;
    if (i >= BDIM * GPR) return;
    int b = i / GPR, g = i % GPR;
    unsigned short* dst = ain0 + (size_t)b * 5376 + 1232 + g * 8;
    if (g < 512) {
        const float* xp = x + (size_t)b * 4096 + g * 8;
        float4 lo = *(const float4*)xp, hi = *(const float4*)(xp + 4);
        union { unsigned short u[8]; uint4 v; } t;
        t.u[0] = f2bf(lo.x); t.u[1] = f2bf(lo.y); t.u[2] = f2bf(lo.z); t.u[3] = f2bf(lo.w);
        t.u[4] = f2bf(hi.x); t.u[5] = f2bf(hi.y); t.u[6] = f2bf(hi.z); t.u[7] = f2bf(hi.w);
        *(uint4*)dst = t.v;
    } else {
        *(uint4*)dst = make_uint4(0u, 0u, 0u, 0u);
    }
}

// ---- pack x -> Ain1[b][t*1344 + 308 .. ]: genes at [308,1332), zeros [1332,1344)
__global__ __launch_bounds__(256) void pack_ain1(const float* __restrict__ x,
                                                 unsigned short* __restrict__ ain1) {
    const int UPT = 259;  // 4-elem units per term
    int i = blockIdx.x * 256 + threadIdx.x;
    if (i >= BDIM * 4 * UPT) return;
    int b = i / (4 * UPT), rem = i % (4 * UPT), t = rem / UPT, u = rem % UPT;
    unsigned short* dst = ain1 + (size_t)b * 5376 + t * 1344 + 308 + u * 4;
    if (u < 256) {
        float4 v = *(const float4*)(x + (size_t)b * 4096 + t * 1024 + u * 4);
        union { unsigned short s[4]; uint2 v; } p;
        p.s[0] = f2bf(v.x); p.s[1] = f2bf(v.y); p.s[2] = f2bf(v.z); p.s[3] = f2bf(v.w);
        *(uint2*)dst = p.v;
    } else {
        *(uint2*)dst = make_uint2(0u, 0u);
    }
}

// ---- W[t][I][O] fp32 -> WbT[t][Npad][Kpad] bf16 (rows o>=O and k>=I zeroed) ----
__global__ __launch_bounds__(256) void cvt_w(const float* __restrict__ W,
                                             unsigned short* __restrict__ WbT,
                                             int I, int O, int Npad, int Kpad) {
    __shared__ unsigned short tile[32][33];
    const int t = blockIdx.z;
    const int i0 = blockIdx.x * 32, o0 = blockIdx.y * 32;
    const int c = threadIdx.x & 31, r0 = threadIdx.x >> 5;
    const float* Wt = W + (size_t)t * I * O;
    #pragma unroll
    for (int rr = 0; rr < 4; rr++) {
        int i = i0 + r0 + rr * 8, o = o0 + c;
        float v = (i < I && o < O) ? Wt[(size_t)i * O + o] : 0.f;
        tile[r0 + rr * 8][c] = f2bf(v);
    }
    __syncthreads();
    unsigned short* dst = WbT + (size_t)t * Npad * Kpad;
    #pragma unroll
    for (int rr = 0; rr < 4; rr++) {
        int o = o0 + r0 + rr * 8, k = i0 + c;
        if (o < Npad) dst[(size_t)o * Kpad + k] = tile[c][r0 + rr * 8];
    }
}

// ---- small-stage GEMM (s4/s3/s2): VGPR staging, bf16 act + fp32 x inline cvt ----
template <int BN, int BK>
__global__ __launch_bounds__(256) void gemm_small(
    const unsigned short* __restrict__ actb,  // [B][T*C] bf16 (null if C==0)
    const float* __restrict__ x,              // [B][4096] fp32
    const unsigned short* __restrict__ WbT,   // [T][O][Kpad] bf16
    const float* __restrict__ bias,
    unsigned short* __restrict__ h,           // [B][hstride]
    int T, int I, int O, int C, int Gs, int Kpad, int hstride)
{
    const int t  = blockIdx.z;
    const int b0 = blockIdx.y * 64;
    const int o0 = blockIdx.x * BN;
    const int tid = threadIdx.x;
    const int lane = tid & 63;
    const int w = tid >> 6;
    const int l15 = lane & 15;
    const int quad = lane >> 4;

    constexpr int NF = BN / 32;
    const int wm = (w & 1) * 32;
    const int wn = (w >> 1) * (BN / 2);

    __shared__ __align__(16) unsigned short As[64][BK + 8];
    __shared__ __align__(16) unsigned short Bs[BN][BK + 8];

    float4v acc[2][NF];
    #pragma unroll
    for (int a = 0; a < 2; a++)
        #pragma unroll
        for (int b = 0; b < NF; b++)
            acc[a][b] = (float4v){0.f, 0.f, 0.f, 0.f};

    constexpr int GR = BK / 8;
    constexpr int AG = 64 * GR;
    constexpr int BG = BN * GR;
    const size_t actRow = (size_t)T * C;

    for (int k0 = 0; k0 < Kpad; k0 += BK) {
        #pragma unroll
        for (int g = tid; g < AG; g += 256) {
            const int r = g / GR, c8 = g % GR;
            const int k = k0 + c8 * 8;
            const int b = b0 + r;
            uint4 v;
            if (k + 8 <= C) {             // act region (granule-aligned for s3/s2)
                v = *(const uint4*)(actb + (size_t)b * actRow + (size_t)t * C + k);
            } else if (k >= I) {
                v = make_uint4(0u, 0u, 0u, 0u);
            } else {                      // gene region, fp32 -> bf16
                const float* xp = x + (size_t)b * 4096 + (size_t)t * Gs + (k - C);
                float4 lo = *(const float4*)xp, hi = *(const float4*)(xp + 4);
                union { unsigned short u[8]; uint4 v; } tmp;
                tmp.u[0] = f2bf(lo.x); tmp.u[1] = f2bf(lo.y); tmp.u[2] = f2bf(lo.z); tmp.u[3] = f2bf(lo.w);
                tmp.u[4] = f2bf(hi.x); tmp.u[5] = f2bf(hi.y); tmp.u[6] = f2bf(hi.z); tmp.u[7] = f2bf(hi.w);
                v = tmp.v;
            }
            *(uint4*)&As[r][c8 * 8] = v;
        }
        #pragma unroll
        for (int g = tid; g < BG; g += 256) {
            const int n = g / GR, c8 = g % GR;
            const int o = o0 + n;
            uint4 v = make_uint4(0u, 0u, 0u, 0u);
            if (o < O)
                v = *(const uint4*)(WbT + ((size_t)t * O + o) * Kpad + k0 + c8 * 8);
            *(uint4*)&Bs[n][c8 * 8] = v;
        }
        __syncthreads();
        #pragma unroll
        for (int ks = 0; ks < BK / 32; ks++) {
            const int koff = ks * 32 + quad * 8;
            short8 a0 = *(const short8*)&As[wm + l15][koff];
            short8 a1 = *(const short8*)&As[wm + 16 + l15][koff];
            #pragma unroll
            for (int fn = 0; fn < NF; fn++) {
                short8 bf = *(const short8*)&Bs[wn + fn * 16 + l15][koff];
                acc[0][fn] = __builtin_amdgcn_mfma_f32_16x16x32_bf16(a0, bf, acc[0][fn], 0, 0, 0);
                acc[1][fn] = __builtin_amdgcn_mfma_f32_16x16x32_bf16(a1, bf, acc[1][fn], 0, 0, 0);
            }
        }
        __syncthreads();
    }

    #pragma unroll
    for (int fm = 0; fm < 2; fm++)
        #pragma unroll
        for (int fn = 0; fn < NF; fn++)
            #pragma unroll
            for (int r = 0; r < 4; r++) {
                int m = wm + fm * 16 + quad * 4 + r;
                int o = o0 + wn + fn * 16 + l15;
                if (o < O) {
                    float v = acc[fm][fn][r] + bias[t * O + o];
                    h[(size_t)(b0 + m) * hstride + (size_t)t * O + o] = f2bf(v);
                }
            }
}

// ---- big-stage GEMM (s1/s0): 128-row tile, BK=32, global_load_lds, split-K ----
// LDS granule layout: pos within row = kg ^ ((row>>1)&3)  => <=2-way bank alias.
template <int BN>
__global__ __launch_bounds__(256) void gemm_split(
    const unsigned short* __restrict__ A,     // [2048][aStride] bf16 (zero-padded)
    const unsigned short* __restrict__ WbT,   // [T][Npad][Kpad] bf16 (zero-padded)
    float* __restrict__ partial,              // [KS][2048][TNpad]
    int aStride, int tStride, int Kpad, int Npad, int KS, int TNpad)
{
    const int tid = threadIdx.x;
    const int lane = tid & 63, w = tid >> 6;
    const int l15 = lane & 15, quad = lane >> 4;
    const int n0 = blockIdx.x * BN;
    const int b0 = blockIdx.y * 128;
    const int ksIdx = blockIdx.z % KS;
    const int t = blockIdx.z / KS;

    __shared__ __align__(16) unsigned short As[128 * 32];
    __shared__ __align__(16) unsigned short Bs[BN * 32];

    const int S = Kpad >> 5;            // total 32-wide K steps
    const int qb = S / KS, rb = S % KS;
    const int beg = ksIdx * qb + (ksIdx < rb ? ksIdx : rb);
    const int cnt = qb + (ksIdx < rb ? 1 : 0);

    constexpr int NF = BN / 32;
    const int wm = (w & 1) * 64;
    const int wn = (w >> 1) * (BN / 2);

    float4v acc[4][NF];
    #pragma unroll
    for (int a = 0; a < 4; a++)
        #pragma unroll
        for (int b = 0; b < NF; b++)
            acc[a][b] = (float4v){0.f, 0.f, 0.f, 0.f};

    // staging sources (per-lane) + LDS bases (wave-uniform)
    const int GA0 = (w * 2) * 64 + lane, GA1 = GA0 + 64;
    const int rA0 = GA0 >> 2, rA1 = GA1 >> 2;
    const int kgA0 = (GA0 & 3) ^ ((rA0 >> 1) & 3);
    const int kgA1 = (GA1 & 3) ^ ((rA1 >> 1) & 3);
    const unsigned short* aS0 = A + (size_t)(b0 + rA0) * aStride + (size_t)t * tStride + kgA0 * 8;
    const unsigned short* aS1 = A + (size_t)(b0 + rA1) * aStride + (size_t)t * tStride + kgA1 * 8;
    unsigned short* lA0 = &As[(w * 2 + 0) * 512];
    unsigned short* lA1 = &As[(w * 2 + 1) * 512];

    const unsigned short* bS0;
    const unsigned short* bS1 = nullptr;
    unsigned short* lB0;
    unsigned short* lB1 = nullptr;
    if (BN == 64) {
        const int G = w * 64 + lane;
        const int r = G >> 2, kg = (G & 3) ^ ((r >> 1) & 3);
        bS0 = WbT + ((size_t)t * Npad + n0 + r) * Kpad + kg * 8;
        lB0 = &Bs[w * 512];
    } else {
        const int G0 = (w * 2) * 64 + lane, G1 = G0 + 64;
        const int r0 = G0 >> 2, r1 = G1 >> 2;
        bS0 = WbT + ((size_t)t * Npad + n0 + r0) * Kpad + ((G0 & 3) ^ ((r0 >> 1) & 3)) * 8;
        bS1 = WbT + ((size_t)t * Npad + n0 + r1) * Kpad + ((G1 & 3) ^ ((r1 >> 1) & 3)) * 8;
        lB0 = &Bs[(w * 2 + 0) * 512];
        lB1 = &Bs[(w * 2 + 1) * 512];
    }

    for (int s = 0; s < cnt; s++) {
        const int k0 = (beg + s) << 5;
        __syncthreads();                       // prev MFMA reads done before overwrite
        stage16(aS0 + k0, lA0, lane);
        stage16(aS1 + k0, lA1, lane);
        stage16(bS0 + k0, lB0, lane);
        if (BN == 128) stage16(bS1 + k0, lB1, lane);
        __syncthreads();                       // drains vmcnt -> LDS ready

        short8 af[4];
        #pragma unroll
        for (int fm = 0; fm < 4; fm++) {
            int m = wm + fm * 16 + l15;
            int pos = quad ^ ((m >> 1) & 3);
            af[fm] = *(const short8*)&As[(m * 4 + pos) * 8];
        }
        short8 bfr[NF];
        #pragma unroll
        for (int fn = 0; fn < NF; fn++) {
            int n = wn + fn * 16 + l15;
            int pos = quad ^ ((n >> 1) & 3);
            bfr[fn] = *(const short8*)&Bs[(n * 4 + pos) * 8];
        }
        #pragma unroll
        for (int fm = 0; fm < 4; fm++)
            #pragma unroll
            for (int fn = 0; fn < NF; fn++)
                acc[fm][fn] = __builtin_amdgcn_mfma_f32_16x16x32_bf16(af[fm], bfr[fn], acc[fm][fn], 0, 0, 0);
    }

    const size_t pBase = ((size_t)ksIdx * BDIM + b0) * TNpad + (size_t)t * Npad + n0;
    #pragma unroll
    for (int fm = 0; fm < 4; fm++)
        #pragma unroll
        for (int r = 0; r < 4; r++) {
            const int m = wm + fm * 16 + quad * 4 + r;
            float* prow = partial + pBase + (size_t)m * TNpad + wn;
            #pragma unroll
            for (int fn = 0; fn < NF; fn++)
                prow[fn * 16 + l15] = acc[fm][fn][r];
        }
}

// ---- split-K reduce + bias + bf16 store ----
__global__ __launch_bounds__(256) void reduce_split(
    const float* __restrict__ partial, const float* __restrict__ bias,
    unsigned short* __restrict__ h, int T, int O, int Npad, int KS, int hstride)
{
    const long long total = (long long)BDIM * T * O;
    long long i = (long long)blockIdx.x * 256 + threadIdx.x;
    if (i >= total) return;
    int b = (int)(i / (T * O));
    int col = (int)(i % (T * O));
    int t = col / O, o = col % O;
    const size_t TNpad = (size_t)T * Npad;
    const float* p = partial + (size_t)b * TNpad + (size_t)t * Npad + o;
    float s = 0.f;
    for (int ks = 0; ks < KS; ks++) s += p[(size_t)ks * BDIM * TNpad];
    h[(size_t)b * hstride + col] = f2bf(s + bias[col]);
}

// ---- BN batch sums: chunked atomic reduce over B ----
__global__ __launch_bounds__(256) void bn_stats(const unsigned short* __restrict__ h,
                                                float* __restrict__ acc, int TO, int hstride) {
    int col = blockIdx.x * 256 + threadIdx.x;
    if (col >= TO) return;
    const unsigned short* p = h + (size_t)blockIdx.y * 128 * hstride + col;
    float s = 0.f, s2 = 0.f;
    #pragma unroll 4
    for (int b = 0; b < 128; b++) {
        float v = bf2f(p[(size_t)b * hstride]);
        s += v; s2 += v * v;
    }
    atomicAdd(&acc[col], s);
    atomicAdd(&acc[TO + col], s2);
}

// ---- BN(final fused) + tanh + strided act store + head ----
__global__ __launch_bounds__(256) void bn_tanh_head(
    const unsigned short* __restrict__ h, const float* __restrict__ stats,
    const float* __restrict__ g, const float* __restrict__ bb,
    const float* __restrict__ hw, const float* __restrict__ hb,
    unsigned short* __restrict__ actOut, float* __restrict__ out,
    int T, int O, int hstride, int aRow, int GT, int GS, int head_off)
{
    int wid  = (blockIdx.x * 256 + threadIdx.x) >> 6;
    int lane = threadIdx.x & 63;
    int b = wid / T;
    int t = wid % T;
    const int TO = T * O;
    const size_t hbase = (size_t)b * hstride + (size_t)t * O;
    const size_t abase = (size_t)b * aRow + (size_t)(t / GT) * GS + (size_t)(t % GT) * O;
    float hsum = 0.f;
    for (int o = lane; o < O; o += 64) {
        int col = t * O + o;
        float mu = stats[col] * (1.f / BDIM);
        float var = stats[TO + col] * (1.f / BDIM) - mu * mu;
        float rsig = rsqrtf(var + 1e-5f);
        float a = tanhf((bf2f(h[hbase + o]) - mu) * rsig * g[col] + bb[col]);
        actOut[abase + o] = f2bf(a);
        hsum += a * hw[col];
    }
    #pragma unroll
    for (int off = 32; off > 0; off >>= 1) hsum += __shfl_down(hsum, off, 64);
    if (lane == 0) out[(size_t)b * OUTW + head_off + t] = hsum + hb[t];
}

extern "C" void kernel_launch(void* const* d_in, const int* in_sizes, int n_in,
                              void* d_out, int out_size, void* d_ws, size_t ws_size,
                              hipStream_t stream)
{
    const float* x = (const float*)d_in[0];
    float* out = (float*)d_out;
    char* ws = (char*)d_ws;

    // ws layout (bytes); total 89,104,384 (~89.1 MB)
    unsigned short* wbt  = (unsigned short*)(ws);              // 13,762,560 (s0 WbT max)
    unsigned short* ain0 = (unsigned short*)(ws + 13762560);   // 22,020,096 (2048x5376)
    unsigned short* bufA = (unsigned short*)(ws + 35782656);   // 20,971,520 (h4/act4 2048x5120)
    unsigned short* bufB = (unsigned short*)(ws + 56754176);   //  5,242,880 (h3/act3 2048x1280)
    unsigned short* ain1 = (unsigned short*)(ws + 61997056);   // 22,020,096 (2048x5376)
    unsigned short* bufC = (unsigned short*)(ws + 84017152);   //  5,046,272 (h2/h1/h0 2048x1232)
    float*          stats= (float*)(ws + 89063424);            //     40,960
    // split-K partials overlay bufA[..bufB..ain1] (dead by the time they're used):
    //   s1: 2*2048*1280*4 = 20,971,520 (== bufA)   s0: 4*2048*1280*4 = 41,943,040
    float* partial = (float*)(ws + 35782656);

    // x-derived packs (independent of stages; act parts filled later by tanh)
    pack_ain0<<<(BDIM * 518 + 255) / 256, 256, 0, stream>>>(x, ain0);
    pack_ain1<<<(BDIM * 4 * 259 + 255) / 256, 256, 0, stream>>>(x, ain1);

    const float* W4 = (const float*)d_in[1];  const float* b4 = (const float*)d_in[2];
    const float* g4 = (const float*)d_in[3];  const float* bb4 = (const float*)d_in[4];
    const float* hw4 = (const float*)d_in[5]; const float* hb4 = (const float*)d_in[6];
    const float* W3 = (const float*)d_in[7];  const float* b3 = (const float*)d_in[8];
    const float* g3 = (const float*)d_in[9];  const float* bb3 = (const float*)d_in[10];
    const float* hw3 = (const float*)d_in[11]; const float* hb3 = (const float*)d_in[12];
    const float* W2 = (const float*)d_in[13]; const float* b2 = (const float*)d_in[14];
    const float* g2 = (const float*)d_in[15]; const float* bb2 = (const float*)d_in[16];
    const float* hw2 = (const float*)d_in[17]; const float* hb2 = (const float*)d_in[18];
    const float* W1 = (const float*)d_in[19]; const float* b1 = (const float*)d_in[20];
    const float* g1 = (const float*)d_in[21]; const float* bb1 = (const float*)d_in[22];
    const float* hw1 = (const float*)d_in[23]; const float* hb1 = (const float*)d_in[24];
    const float* W0 = (const float*)d_in[25]; const float* b0_ = (const float*)d_in[26];
    const float* g0 = (const float*)d_in[27]; const float* bb0 = (const float*)d_in[28];
    const float* hw0 = (const float*)d_in[29]; const float* hb0 = (const float*)d_in[30];

    // ---------------- s4: T=256 I=16 O=20 C=0 Gs=16 Kpad=32 ----------------
    cvt_w<<<dim3(1, 1, 256), 256, 0, stream>>>(W4, wbt, 16, 20, 20, 32);
    gemm_small<32, 32><<<dim3(1, 32, 256), 256, 0, stream>>>(nullptr, x, wbt, b4, bufA,
                                                             256, 16, 20, 0, 16, 32, 5120);
    hipMemsetAsync(stats, 0, 2 * 5120 * sizeof(float), stream);
    bn_stats<<<dim3(20, 16), 256, 0, stream>>>(bufA, stats, 5120, 5120);
    bn_tanh_head<<<BDIM * 256 / 4, 256, 0, stream>>>(bufA, stats, g4, bb4, hw4, hb4,
                                                     bufA, out, 256, 20, 5120, 5120, 256, 0, 0);

    // ---------------- s3: T=64 I=144 O=20 C=80 Gs=64 Kpad=192 ----------------
    cvt_w<<<dim3(6, 1, 64), 256, 0, stream>>>(W3, wbt, 144, 20, 20, 192);
    gemm_small<32, 64><<<dim3(1, 32, 64), 256, 0, stream>>>(bufA, x, wbt, b3, bufB,
                                                            64, 144, 20, 80, 64, 192, 1280);
    hipMemsetAsync(stats, 0, 2 * 1280 * sizeof(float), stream);
    bn_stats<<<dim3(5, 16), 256, 0, stream>>>(bufB, stats, 1280, 1280);
    bn_tanh_head<<<BDIM * 64 / 4, 256, 0, stream>>>(bufB, stats, g3, bb3, hw3, hb3,
                                                    bufB, out, 64, 20, 1280, 1280, 64, 0, 256);

    // ---------------- s2: T=16 I=336 O=77 C=80 Gs=256 Kpad=384 ----------------
    cvt_w<<<dim3(12, 3, 16), 256, 0, stream>>>(W2, wbt, 336, 77, 77, 384);
    gemm_small<64, 64><<<dim3(2, 32, 16), 256, 0, stream>>>(bufB, x, wbt, b2, bufC,
                                                            16, 336, 77, 80, 256, 384, 1232);
    hipMemsetAsync(stats, 0, 2 * 1232 * sizeof(float), stream);
    bn_stats<<<dim3(5, 16), 256, 0, stream>>>(bufC, stats, 1232, 1232);
    // act2 -> Ain1 strided: col = (t/4)*1344 + (t%4)*77 + o
    bn_tanh_head<<<BDIM * 16 / 4, 256, 0, stream>>>(bufC, stats, g2, bb2, hw2, hb2,
                                                    ain1, out, 16, 77, 1232, 5376, 4, 1344, 320);

    // ---------------- s1: T=4 I=1332 O=308 Kpad=1344 Npad=320 KS=2 ----------------
    cvt_w<<<dim3(42, 10, 4), 256, 0, stream>>>(W1, wbt, 1332, 308, 320, 1344);
    gemm_split<64><<<dim3(5, 16, 8), 256, 0, stream>>>(ain1, wbt, partial,
                                                       5376, 1344, 1344, 320, 2, 1280);
    reduce_split<<<(BDIM * 4 * 308 + 255) / 256, 256, 0, stream>>>(partial, b1, bufC,
                                                                   4, 308, 320, 2, 1232);
    hipMemsetAsync(stats, 0, 2 * 1232 * sizeof(float), stream);
    bn_stats<<<dim3(5, 16), 256, 0, stream>>>(bufC, stats, 1232, 1232);
    // act1 -> Ain0 cols [0,1232): col = t*308 + o
    bn_tanh_head<<<BDIM * 4 / 4, 256, 0, stream>>>(bufC, stats, g1, bb1, hw1, hb1,
                                                   ain0, out, 4, 308, 1232, 5376, 4, 0, 336);

    // ---------------- s0: T=1 I=5328 O=1229 Kpad=5376 Npad=1280 KS=4 ----------------
    cvt_w<<<dim3(168, 40, 1), 256, 0, stream>>>(W0, wbt, 5328, 1229, 1280, 5376);
    gemm_split<128><<<dim3(10, 16, 4), 256, 0, stream>>>(ain0, wbt, partial,
                                                         5376, 0, 5376, 1280, 4, 1280);
    reduce_split<<<(BDIM * 1229 + 255) / 256, 256, 0, stream>>>(partial, b0_, bufC,
                                                                1, 1229, 1280, 4, 1232);
    hipMemsetAsync(stats, 0, 2 * 1229 * sizeof(float), stream);
    bn_stats<<<dim3(5, 16), 256, 0, stream>>>(bufC, stats, 1229, 1232);
    bn_tanh_head<<<BDIM / 4, 256, 0, stream>>>(bufC, stats, g0, bb0, hw0, hb0,
                                               bufC, out, 1, 1229, 1232, 1232, 1, 0, 340);
}

// Round 4
// 609.930 us; speedup vs baseline: 2.7231x; 1.0117x over previous
//
#include <hip/hip_runtime.h>
#include <hip/hip_bf16.h>

// DCell forward, bf16-MFMA, m97-style split-K GEMM for the two big stages.
// Stages (T, I, O, C=act chans, Gs): s4(256,16,20,0,16) s3(64,144,20,80,64)
//  s2(16,336,77,80,256) s1(4,1332,308,308,1024) s0(1,5328,1229,1232,4096)
// s4/s3/s2: gemm_small (VGPR staging; tiny GEMMs, many blocks).
// s1/s0: inputs pre-packed to contiguous zero-padded bf16 rows (Ain1/Ain0);
//        gemm_split: 128-row tiles, BK=32, global_load_lds(16B) staging into
//        XOR-swizzled LDS, split-K fp32 partials + reduce.
// BN per stage fused: memset+bn_stats (atomic chunk sums) + bn_tanh_head
// (mu/rsig inline, fast exp2-based tanh, act store [optionally strided] + head).
// Round-4 change: thread-per-(b,t) tanh variant for O=20 stages (s4/s3) —
// the wave variant wasted 44/64 lanes and 131 us on libm tanhf.

#define BDIM 2048
#define OUTW 341

typedef __attribute__((ext_vector_type(8))) short short8;   // 8 bf16 = 4 VGPRs
typedef __attribute__((ext_vector_type(4))) float float4v;  // MFMA acc

static __device__ __forceinline__ unsigned short f2bf(float f) {
    union { float f; unsigned u; } c{f};
    unsigned r = c.u + 0x7FFF + ((c.u >> 16) & 1);  // RNE
    return (unsigned short)(r >> 16);
}
static __device__ __forceinline__ float bf2f(unsigned short s) {
    union { unsigned u; float f; } c{(unsigned)s << 16};
    return c.f;
}

// tanh via v_exp_f32 + v_rcp_f32: ~7 VALU ops, ~1e-7 rel error.
static __device__ __forceinline__ float fast_tanh(float x) {
    float ax = __builtin_fabsf(x);
    float e  = __builtin_amdgcn_exp2f(ax * 2.8853900817779268f);  // e^{2|x|}
    float r  = 1.f - 2.f * __builtin_amdgcn_rcpf(e + 1.f);
    return __builtin_copysignf(r, x);
}

// async global->LDS, 16B/lane. LDS dest semantics: wave-uniform base + lane*16.
static __device__ __forceinline__ void stage16(const void* g, void* ldsBase, int lane) {
#if __has_builtin(__builtin_amdgcn_global_load_lds)
    __builtin_amdgcn_global_load_lds(
        (const __attribute__((address_space(1))) unsigned int*)(uintptr_t)g,
        (__attribute__((address_space(3))) unsigned int*)(unsigned int)(uintptr_t)ldsBase,
        16, 0, 0);
#else
    *(uint4*)((char*)ldsBase + lane * 16) = *(const uint4*)g;
#endif
}

// ---- pack x (fp32) -> Ain0[b][5376]: cols [1232,5328)=x genes, [5328,5376)=0
__global__ __launch_bounds__(256) void pack_ain0(const float* __restrict__ x,
                                                 unsigned short* __restrict__ ain0) {
    const int GPR = 518;  // 16B granules per row
    int i = blockIdx.x * 256 + threadIdx.x;
    if (i >= BDIM * GPR) return;
    int b = i / GPR, g = i % GPR;
    unsigned short* dst = ain0 + (size_t)b * 5376 + 1232 + g * 8;
    if (g < 512) {
        const float* xp = x + (size_t)b * 4096 + g * 8;
        float4 lo = *(const float4*)xp, hi = *(const float4*)(xp + 4);
        union { unsigned short u[8]; uint4 v; } t;
        t.u[0] = f2bf(lo.x); t.u[1] = f2bf(lo.y); t.u[2] = f2bf(lo.z); t.u[3] = f2bf(lo.w);
        t.u[4] = f2bf(hi.x); t.u[5] = f2bf(hi.y); t.u[6] = f2bf(hi.z); t.u[7] = f2bf(hi.w);
        *(uint4*)dst = t.v;
    } else {
        *(uint4*)dst = make_uint4(0u, 0u, 0u, 0u);
    }
}

// ---- pack x -> Ain1[b][t*1344 + 308 .. ]: genes at [308,1332), zeros [1332,1344)
__global__ __launch_bounds__(256) void pack_ain1(const float* __restrict__ x,
                                                 unsigned short* __restrict__ ain1) {
    const int UPT = 259;  // 4-elem units per term
    int i = blockIdx.x * 256 + threadIdx.x;
    if (i >= BDIM * 4 * UPT) return;
    int b = i / (4 * UPT), rem = i % (4 * UPT), t = rem / UPT, u = rem % UPT;
    unsigned short* dst = ain1 + (size_t)b * 5376 + t * 1344 + 308 + u * 4;
    if (u < 256) {
        float4 v = *(const float4*)(x + (size_t)b * 4096 + t * 1024 + u * 4);
        union { unsigned short s[4]; uint2 v; } p;
        p.s[0] = f2bf(v.x); p.s[1] = f2bf(v.y); p.s[2] = f2bf(v.z); p.s[3] = f2bf(v.w);
        *(uint2*)dst = p.v;
    } else {
        *(uint2*)dst = make_uint2(0u, 0u);
    }
}

// ---- W[t][I][O] fp32 -> WbT[t][Npad][Kpad] bf16 (rows o>=O and k>=I zeroed) ----
__global__ __launch_bounds__(256) void cvt_w(const float* __restrict__ W,
                                             unsigned short* __restrict__ WbT,
                                             int I, int O, int Npad, int Kpad) {
    __shared__ unsigned short tile[32][33];
    const int t = blockIdx.z;
    const int i0 = blockIdx.x * 32, o0 = blockIdx.y * 32;
    const int c = threadIdx.x & 31, r0 = threadIdx.x >> 5;
    const float* Wt = W + (size_t)t * I * O;
    #pragma unroll
    for (int rr = 0; rr < 4; rr++) {
        int i = i0 + r0 + rr * 8, o = o0 + c;
        float v = (i < I && o < O) ? Wt[(size_t)i * O + o] : 0.f;
        tile[r0 + rr * 8][c] = f2bf(v);
    }
    __syncthreads();
    unsigned short* dst = WbT + (size_t)t * Npad * Kpad;
    #pragma unroll
    for (int rr = 0; rr < 4; rr++) {
        int o = o0 + r0 + rr * 8, k = i0 + c;
        if (o < Npad) dst[(size_t)o * Kpad + k] = tile[c][r0 + rr * 8];
    }
}

// ---- small-stage GEMM (s4/s3/s2): VGPR staging, bf16 act + fp32 x inline cvt ----
template <int BN, int BK>
__global__ __launch_bounds__(256) void gemm_small(
    const unsigned short* __restrict__ actb,  // [B][T*C] bf16 (null if C==0)
    const float* __restrict__ x,              // [B][4096] fp32
    const unsigned short* __restrict__ WbT,   // [T][O][Kpad] bf16
    const float* __restrict__ bias,
    unsigned short* __restrict__ h,           // [B][hstride]
    int T, int I, int O, int C, int Gs, int Kpad, int hstride)
{
    const int t  = blockIdx.z;
    const int b0 = blockIdx.y * 64;
    const int o0 = blockIdx.x * BN;
    const int tid = threadIdx.x;
    const int lane = tid & 63;
    const int w = tid >> 6;
    const int l15 = lane & 15;
    const int quad = lane >> 4;

    constexpr int NF = BN / 32;
    const int wm = (w & 1) * 32;
    const int wn = (w >> 1) * (BN / 2);

    __shared__ __align__(16) unsigned short As[64][BK + 8];
    __shared__ __align__(16) unsigned short Bs[BN][BK + 8];

    float4v acc[2][NF];
    #pragma unroll
    for (int a = 0; a < 2; a++)
        #pragma unroll
        for (int b = 0; b < NF; b++)
            acc[a][b] = (float4v){0.f, 0.f, 0.f, 0.f};

    constexpr int GR = BK / 8;
    constexpr int AG = 64 * GR;
    constexpr int BG = BN * GR;
    const size_t actRow = (size_t)T * C;

    for (int k0 = 0; k0 < Kpad; k0 += BK) {
        #pragma unroll
        for (int g = tid; g < AG; g += 256) {
            const int r = g / GR, c8 = g % GR;
            const int k = k0 + c8 * 8;
            const int b = b0 + r;
            uint4 v;
            if (k + 8 <= C) {             // act region (granule-aligned for s3/s2)
                v = *(const uint4*)(actb + (size_t)b * actRow + (size_t)t * C + k);
            } else if (k >= I) {
                v = make_uint4(0u, 0u, 0u, 0u);
            } else {                      // gene region, fp32 -> bf16
                const float* xp = x + (size_t)b * 4096 + (size_t)t * Gs + (k - C);
                float4 lo = *(const float4*)xp, hi = *(const float4*)(xp + 4);
                union { unsigned short u[8]; uint4 v; } tmp;
                tmp.u[0] = f2bf(lo.x); tmp.u[1] = f2bf(lo.y); tmp.u[2] = f2bf(lo.z); tmp.u[3] = f2bf(lo.w);
                tmp.u[4] = f2bf(hi.x); tmp.u[5] = f2bf(hi.y); tmp.u[6] = f2bf(hi.z); tmp.u[7] = f2bf(hi.w);
                v = tmp.v;
            }
            *(uint4*)&As[r][c8 * 8] = v;
        }
        #pragma unroll
        for (int g = tid; g < BG; g += 256) {
            const int n = g / GR, c8 = g % GR;
            const int o = o0 + n;
            uint4 v = make_uint4(0u, 0u, 0u, 0u);
            if (o < O)
                v = *(const uint4*)(WbT + ((size_t)t * O + o) * Kpad + k0 + c8 * 8);
            *(uint4*)&Bs[n][c8 * 8] = v;
        }
        __syncthreads();
        #pragma unroll
        for (int ks = 0; ks < BK / 32; ks++) {
            const int koff = ks * 32 + quad * 8;
            short8 a0 = *(const short8*)&As[wm + l15][koff];
            short8 a1 = *(const short8*)&As[wm + 16 + l15][koff];
            #pragma unroll
            for (int fn = 0; fn < NF; fn++) {
                short8 bf = *(const short8*)&Bs[wn + fn * 16 + l15][koff];
                acc[0][fn] = __builtin_amdgcn_mfma_f32_16x16x32_bf16(a0, bf, acc[0][fn], 0, 0, 0);
                acc[1][fn] = __builtin_amdgcn_mfma_f32_16x16x32_bf16(a1, bf, acc[1][fn], 0, 0, 0);
            }
        }
        __syncthreads();
    }

    #pragma unroll
    for (int fm = 0; fm < 2; fm++)
        #pragma unroll
        for (int fn = 0; fn < NF; fn++)
            #pragma unroll
            for (int r = 0; r < 4; r++) {
                int m = wm + fm * 16 + quad * 4 + r;
                int o = o0 + wn + fn * 16 + l15;
                if (o < O) {
                    float v = acc[fm][fn][r] + bias[t * O + o];
                    h[(size_t)(b0 + m) * hstride + (size_t)t * O + o] = f2bf(v);
                }
            }
}

// ---- big-stage GEMM (s1/s0): 128-row tile, BK=32, global_load_lds, split-K ----
// LDS granule layout: pos within row = kg ^ ((row>>1)&3)  => <=2-way bank alias.
template <int BN>
__global__ __launch_bounds__(256) void gemm_split(
    const unsigned short* __restrict__ A,     // [2048][aStride] bf16 (zero-padded)
    const unsigned short* __restrict__ WbT,   // [T][Npad][Kpad] bf16 (zero-padded)
    float* __restrict__ partial,              // [KS][2048][TNpad]
    int aStride, int tStride, int Kpad, int Npad, int KS, int TNpad)
{
    const int tid = threadIdx.x;
    const int lane = tid & 63, w = tid >> 6;
    const int l15 = lane & 15, quad = lane >> 4;
    const int n0 = blockIdx.x * BN;
    const int b0 = blockIdx.y * 128;
    const int ksIdx = blockIdx.z % KS;
    const int t = blockIdx.z / KS;

    __shared__ __align__(16) unsigned short As[128 * 32];
    __shared__ __align__(16) unsigned short Bs[BN * 32];

    const int S = Kpad >> 5;            // total 32-wide K steps
    const int qb = S / KS, rb = S % KS;
    const int beg = ksIdx * qb + (ksIdx < rb ? ksIdx : rb);
    const int cnt = qb + (ksIdx < rb ? 1 : 0);

    constexpr int NF = BN / 32;
    const int wm = (w & 1) * 64;
    const int wn = (w >> 1) * (BN / 2);

    float4v acc[4][NF];
    #pragma unroll
    for (int a = 0; a < 4; a++)
        #pragma unroll
        for (int b = 0; b < NF; b++)
            acc[a][b] = (float4v){0.f, 0.f, 0.f, 0.f};

    // staging sources (per-lane) + LDS bases (wave-uniform)
    const int GA0 = (w * 2) * 64 + lane, GA1 = GA0 + 64;
    const int rA0 = GA0 >> 2, rA1 = GA1 >> 2;
    const int kgA0 = (GA0 & 3) ^ ((rA0 >> 1) & 3);
    const int kgA1 = (GA1 & 3) ^ ((rA1 >> 1) & 3);
    const unsigned short* aS0 = A + (size_t)(b0 + rA0) * aStride + (size_t)t * tStride + kgA0 * 8;
    const unsigned short* aS1 = A + (size_t)(b0 + rA1) * aStride + (size_t)t * tStride + kgA1 * 8;
    unsigned short* lA0 = &As[(w * 2 + 0) * 512];
    unsigned short* lA1 = &As[(w * 2 + 1) * 512];

    const unsigned short* bS0;
    const unsigned short* bS1 = nullptr;
    unsigned short* lB0;
    unsigned short* lB1 = nullptr;
    if (BN == 64) {
        const int G = w * 64 + lane;
        const int r = G >> 2, kg = (G & 3) ^ ((r >> 1) & 3);
        bS0 = WbT + ((size_t)t * Npad + n0 + r) * Kpad + kg * 8;
        lB0 = &Bs[w * 512];
    } else {
        const int G0 = (w * 2) * 64 + lane, G1 = G0 + 64;
        const int r0 = G0 >> 2, r1 = G1 >> 2;
        bS0 = WbT + ((size_t)t * Npad + n0 + r0) * Kpad + ((G0 & 3) ^ ((r0 >> 1) & 3)) * 8;
        bS1 = WbT + ((size_t)t * Npad + n0 + r1) * Kpad + ((G1 & 3) ^ ((r1 >> 1) & 3)) * 8;
        lB0 = &Bs[(w * 2 + 0) * 512];
        lB1 = &Bs[(w * 2 + 1) * 512];
    }

    for (int s = 0; s < cnt; s++) {
        const int k0 = (beg + s) << 5;
        __syncthreads();                       // prev MFMA reads done before overwrite
        stage16(aS0 + k0, lA0, lane);
        stage16(aS1 + k0, lA1, lane);
        stage16(bS0 + k0, lB0, lane);
        if (BN == 128) stage16(bS1 + k0, lB1, lane);
        __syncthreads();                       // drains vmcnt -> LDS ready

        short8 af[4];
        #pragma unroll
        for (int fm = 0; fm < 4; fm++) {
            int m = wm + fm * 16 + l15;
            int pos = quad ^ ((m >> 1) & 3);
            af[fm] = *(const short8*)&As[(m * 4 + pos) * 8];
        }
        short8 bfr[NF];
        #pragma unroll
        for (int fn = 0; fn < NF; fn++) {
            int n = wn + fn * 16 + l15;
            int pos = quad ^ ((n >> 1) & 3);
            bfr[fn] = *(const short8*)&Bs[(n * 4 + pos) * 8];
        }
        #pragma unroll
        for (int fm = 0; fm < 4; fm++)
            #pragma unroll
            for (int fn = 0; fn < NF; fn++)
                acc[fm][fn] = __builtin_amdgcn_mfma_f32_16x16x32_bf16(af[fm], bfr[fn], acc[fm][fn], 0, 0, 0);
    }

    const size_t pBase = ((size_t)ksIdx * BDIM + b0) * TNpad + (size_t)t * Npad + n0;
    #pragma unroll
    for (int fm = 0; fm < 4; fm++)
        #pragma unroll
        for (int r = 0; r < 4; r++) {
            const int m = wm + fm * 16 + quad * 4 + r;
            float* prow = partial + pBase + (size_t)m * TNpad + wn;
            #pragma unroll
            for (int fn = 0; fn < NF; fn++)
                prow[fn * 16 + l15] = acc[fm][fn][r];
        }
}

// ---- split-K reduce + bias + bf16 store ----
__global__ __launch_bounds__(256) void reduce_split(
    const float* __restrict__ partial, const float* __restrict__ bias,
    unsigned short* __restrict__ h, int T, int O, int Npad, int KS, int hstride)
{
    const long long total = (long long)BDIM * T * O;
    long long i = (long long)blockIdx.x * 256 + threadIdx.x;
    if (i >= total) return;
    int b = (int)(i / (T * O));
    int col = (int)(i % (T * O));
    int t = col / O, o = col % O;
    const size_t TNpad = (size_t)T * Npad;
    const float* p = partial + (size_t)b * TNpad + (size_t)t * Npad + o;
    float s = 0.f;
    for (int ks = 0; ks < KS; ks++) s += p[(size_t)ks * BDIM * TNpad];
    h[(size_t)b * hstride + col] = f2bf(s + bias[col]);
}

// ---- BN batch sums: chunked atomic reduce over B ----
__global__ __launch_bounds__(256) void bn_stats(const unsigned short* __restrict__ h,
                                                float* __restrict__ acc, int TO, int hstride) {
    int col = blockIdx.x * 256 + threadIdx.x;
    if (col >= TO) return;
    const unsigned short* p = h + (size_t)blockIdx.y * 128 * hstride + col;
    float s = 0.f, s2 = 0.f;
    #pragma unroll 4
    for (int b = 0; b < 128; b++) {
        float v = bf2f(p[(size_t)b * hstride]);
        s += v; s2 += v * v;
    }
    atomicAdd(&acc[col], s);
    atomicAdd(&acc[TO + col], s2);
}

// ---- BN(final fused) + tanh + strided act store + head — WAVE variant (large O) ----
__global__ __launch_bounds__(256) void bn_tanh_head(
    const unsigned short* __restrict__ h, const float* __restrict__ stats,
    const float* __restrict__ g, const float* __restrict__ bb,
    const float* __restrict__ hw, const float* __restrict__ hb,
    unsigned short* __restrict__ actOut, float* __restrict__ out,
    int T, int O, int hstride, int aRow, int GT, int GS, int head_off)
{
    int wid  = (blockIdx.x * 256 + threadIdx.x) >> 6;
    int lane = threadIdx.x & 63;
    int b = wid / T;
    int t = wid % T;
    const int TO = T * O;
    const size_t hbase = (size_t)b * hstride + (size_t)t * O;
    const size_t abase = (size_t)b * aRow + (size_t)(t / GT) * GS + (size_t)(t % GT) * O;
    float hsum = 0.f;
    for (int o = lane; o < O; o += 64) {
        int col = t * O + o;
        float mu = stats[col] * (1.f / BDIM);
        float var = stats[TO + col] * (1.f / BDIM) - mu * mu;
        float rsig = rsqrtf(var + 1e-5f);
        float a = fast_tanh((bf2f(h[hbase + o]) - mu) * rsig * g[col] + bb[col]);
        actOut[abase + o] = f2bf(a);
        hsum += a * hw[col];
    }
    #pragma unroll
    for (int off = 32; off > 0; off >>= 1) hsum += __shfl_down(hsum, off, 64);
    if (lane == 0) out[(size_t)b * OUTW + head_off + t] = hsum + hb[t];
}

// ---- THREAD variant (small O, e.g. 20): one thread per (b,t), all lanes active ----
__global__ __launch_bounds__(256) void bn_tanh_head_thr(
    const unsigned short* __restrict__ h, const float* __restrict__ stats,
    const float* __restrict__ g, const float* __restrict__ bb,
    const float* __restrict__ hw, const float* __restrict__ hb,
    unsigned short* __restrict__ actOut, float* __restrict__ out,
    int T, int O, int hstride, int aRow, int head_off)
{
    int idx = blockIdx.x * 256 + threadIdx.x;   // (b,t)
    if (idx >= BDIM * T) return;
    int b = idx / T, t = idx % T;
    const int TO = T * O;
    const size_t hbase = (size_t)b * hstride + (size_t)t * O;
    const size_t abase = (size_t)b * aRow + (size_t)t * O;   // in-place layouts only
    float hsum = 0.f;
    for (int o = 0; o < O; o++) {
        int col = t * O + o;
        float mu = stats[col] * (1.f / BDIM);
        float var = stats[TO + col] * (1.f / BDIM) - mu * mu;
        float rsig = rsqrtf(var + 1e-5f);
        float a = fast_tanh((bf2f(h[hbase + o]) - mu) * rsig * g[col] + bb[col]);
        actOut[abase + o] = f2bf(a);
        hsum += a * hw[col];
    }
    out[(size_t)b * OUTW + head_off + t] = hsum + hb[t];
}

extern "C" void kernel_launch(void* const* d_in, const int* in_sizes, int n_in,
                              void* d_out, int out_size, void* d_ws, size_t ws_size,
                              hipStream_t stream)
{
    const float* x = (const float*)d_in[0];
    float* out = (float*)d_out;
    char* ws = (char*)d_ws;

    // ws layout (bytes); total ~89.1 MB
    unsigned short* wbt  = (unsigned short*)(ws);              // 13,762,560 (s0 WbT max)
    unsigned short* ain0 = (unsigned short*)(ws + 13762560);   // 22,020,096 (2048x5376)
    unsigned short* bufA = (unsigned short*)(ws + 35782656);   // 20,971,520 (h4/act4 2048x5120)
    unsigned short* bufB = (unsigned short*)(ws + 56754176);   //  5,242,880 (h3/act3 2048x1280)
    unsigned short* ain1 = (unsigned short*)(ws + 61997056);   // 22,020,096 (2048x5376)
    unsigned short* bufC = (unsigned short*)(ws + 84017152);   //  5,046,272 (h2/h1/h0 2048x1232)
    float*          stats= (float*)(ws + 89063424);            //     40,960
    // split-K partials overlay bufA.. (dead by use time): s1 20.9MB, s0 41.9MB
    float* partial = (float*)(ws + 35782656);

    pack_ain0<<<(BDIM * 518 + 255) / 256, 256, 0, stream>>>(x, ain0);
    pack_ain1<<<(BDIM * 4 * 259 + 255) / 256, 256, 0, stream>>>(x, ain1);

    const float* W4 = (const float*)d_in[1];  const float* b4 = (const float*)d_in[2];
    const float* g4 = (const float*)d_in[3];  const float* bb4 = (const float*)d_in[4];
    const float* hw4 = (const float*)d_in[5]; const float* hb4 = (const float*)d_in[6];
    const float* W3 = (const float*)d_in[7];  const float* b3 = (const float*)d_in[8];
    const float* g3 = (const float*)d_in[9];  const float* bb3 = (const float*)d_in[10];
    const float* hw3 = (const float*)d_in[11]; const float* hb3 = (const float*)d_in[12];
    const float* W2 = (const float*)d_in[13]; const float* b2 = (const float*)d_in[14];
    const float* g2 = (const float*)d_in[15]; const float* bb2 = (const float*)d_in[16];
    const float* hw2 = (const float*)d_in[17]; const float* hb2 = (const float*)d_in[18];
    const float* W1 = (const float*)d_in[19]; const float* b1 = (const float*)d_in[20];
    const float* g1 = (const float*)d_in[21]; const float* bb1 = (const float*)d_in[22];
    const float* hw1 = (const float*)d_in[23]; const float* hb1 = (const float*)d_in[24];
    const float* W0 = (const float*)d_in[25]; const float* b0_ = (const float*)d_in[26];
    const float* g0 = (const float*)d_in[27]; const float* bb0 = (const float*)d_in[28];
    const float* hw0 = (const float*)d_in[29]; const float* hb0 = (const float*)d_in[30];

    // ---------------- s4: T=256 I=16 O=20 C=0 Gs=16 Kpad=32 ----------------
    cvt_w<<<dim3(1, 1, 256), 256, 0, stream>>>(W4, wbt, 16, 20, 20, 32);
    gemm_small<32, 32><<<dim3(1, 32, 256), 256, 0, stream>>>(nullptr, x, wbt, b4, bufA,
                                                             256, 16, 20, 0, 16, 32, 5120);
    hipMemsetAsync(stats, 0, 2 * 5120 * sizeof(float), stream);
    bn_stats<<<dim3(20, 16), 256, 0, stream>>>(bufA, stats, 5120, 5120);
    bn_tanh_head_thr<<<BDIM * 256 / 256, 256, 0, stream>>>(bufA, stats, g4, bb4, hw4, hb4,
                                                           bufA, out, 256, 20, 5120, 5120, 0);

    // ---------------- s3: T=64 I=144 O=20 C=80 Gs=64 Kpad=192 ----------------
    cvt_w<<<dim3(6, 1, 64), 256, 0, stream>>>(W3, wbt, 144, 20, 20, 192);
    gemm_small<32, 64><<<dim3(1, 32, 64), 256, 0, stream>>>(bufA, x, wbt, b3, bufB,
                                                            64, 144, 20, 80, 64, 192, 1280);
    hipMemsetAsync(stats, 0, 2 * 1280 * sizeof(float), stream);
    bn_stats<<<dim3(5, 16), 256, 0, stream>>>(bufB, stats, 1280, 1280);
    bn_tanh_head_thr<<<BDIM * 64 / 256, 256, 0, stream>>>(bufB, stats, g3, bb3, hw3, hb3,
                                                          bufB, out, 64, 20, 1280, 1280, 256);

    // ---------------- s2: T=16 I=336 O=77 C=80 Gs=256 Kpad=384 ----------------
    cvt_w<<<dim3(12, 3, 16), 256, 0, stream>>>(W2, wbt, 336, 77, 77, 384);
    gemm_small<64, 64><<<dim3(2, 32, 16), 256, 0, stream>>>(bufB, x, wbt, b2, bufC,
                                                            16, 336, 77, 80, 256, 384, 1232);
    hipMemsetAsync(stats, 0, 2 * 1232 * sizeof(float), stream);
    bn_stats<<<dim3(5, 16), 256, 0, stream>>>(bufC, stats, 1232, 1232);
    // act2 -> Ain1 strided: col = (t/4)*1344 + (t%4)*77 + o
    bn_tanh_head<<<BDIM * 16 / 4, 256, 0, stream>>>(bufC, stats, g2, bb2, hw2, hb2,
                                                    ain1, out, 16, 77, 1232, 5376, 4, 1344, 320);

    // ---------------- s1: T=4 I=1332 O=308 Kpad=1344 Npad=320 KS=2 ----------------
    cvt_w<<<dim3(42, 10, 4), 256, 0, stream>>>(W1, wbt, 1332, 308, 320, 1344);
    gemm_split<64><<<dim3(5, 16, 8), 256, 0, stream>>>(ain1, wbt, partial,
                                                       5376, 1344, 1344, 320, 2, 1280);
    reduce_split<<<(BDIM * 4 * 308 + 255) / 256, 256, 0, stream>>>(partial, b1, bufC,
                                                                   4, 308, 320, 2, 1232);
    hipMemsetAsync(stats, 0, 2 * 1232 * sizeof(float), stream);
    bn_stats<<<dim3(5, 16), 256, 0, stream>>>(bufC, stats, 1232, 1232);
    // act1 -> Ain0 cols [0,1232): col = t*308 + o
    bn_tanh_head<<<BDIM * 4 / 4, 256, 0, stream>>>(bufC, stats, g1, bb1, hw1, hb1,
                                                   ain0, out, 4, 308, 1232, 5376, 4, 0, 336);

    // ---------------- s0: T=1 I=5328 O=1229 Kpad=5376 Npad=1280 KS=4 ----------------
    cvt_w<<<dim3(168, 40, 1), 256, 0, stream>>>(W0, wbt, 5328, 1229, 1280, 5376);
    gemm_split<128><<<dim3(10, 16, 4), 256, 0, stream>>>(ain0, wbt, partial,
                                                         5376, 0, 5376, 1280, 4, 1280);
    reduce_split<<<(BDIM * 1229 + 255) / 256, 256, 0, stream>>>(partial, b0_, bufC,
                                                                1, 1229, 1280, 4, 1232);
    hipMemsetAsync(stats, 0, 2 * 1229 * sizeof(float), stream);
    bn_stats<<<dim3(5, 16), 256, 0, stream>>>(bufC, stats, 1229, 1232);
    bn_tanh_head<<<BDIM / 4, 256, 0, stream>>>(bufC, stats, g0, bb0, hw0, hb0,
                                               bufC, out, 1, 1229, 1232, 1232, 1, 0, 340);
}

// Round 5
// 482.879 us; speedup vs baseline: 3.4395x; 1.2631x over previous
//
#include <hip/hip_runtime.h>
#include <hip/hip_bf16.h>

// DCell forward, bf16-MFMA, m97-style split-K GEMM for the two big stages.
// Stages (T, I, O, C=act chans, Gs): s4(256,16,20,0,16) s3(64,144,20,80,64)
//  s2(16,336,77,80,256) s1(4,1332,308,308,1024) s0(1,5328,1229,1232,4096)
// s4/s3/s2: gemm_small (VGPR staging; tiny GEMMs, many blocks).
// s1/s0: inputs pre-packed to contiguous zero-padded bf16 rows (Ain1/Ain0);
//        gemm_split: 128-row tiles, BK=32, global_load_lds(16B) staging into
//        XOR-swizzled LDS, split-K fp32 partials + reduce.
// BN tanh epilogue:
//   s4/s3 (O=20, in-place): bn_scale (per-col scale/shift) + bn_tanh_head_vec
//     (row-contiguous uint2/float4 vectorized, LDS head accum). Round-4's
//     thread-per-(b,t) variant was request-bound (40B-strided scalar loads,
//     VALUBusy 6%, 145us) — this one is fully coalesced.
//   s2/s1/s0: wave variant (coalesced scalar, inline stats), fast_tanh.

#define BDIM 2048
#define OUTW 341

typedef __attribute__((ext_vector_type(8))) short short8;   // 8 bf16 = 4 VGPRs
typedef __attribute__((ext_vector_type(4))) float float4v;  // MFMA acc

static __device__ __forceinline__ unsigned short f2bf(float f) {
    union { float f; unsigned u; } c{f};
    unsigned r = c.u + 0x7FFF + ((c.u >> 16) & 1);  // RNE
    return (unsigned short)(r >> 16);
}
static __device__ __forceinline__ float bf2f(unsigned short s) {
    union { unsigned u; float f; } c{(unsigned)s << 16};
    return c.f;
}

// tanh via v_exp_f32 + v_rcp_f32: ~7 VALU ops, ~1e-7 rel error.
static __device__ __forceinline__ float fast_tanh(float x) {
    float ax = __builtin_fabsf(x);
    float e  = __builtin_amdgcn_exp2f(ax * 2.8853900817779268f);  // e^{2|x|}
    float r  = 1.f - 2.f * __builtin_amdgcn_rcpf(e + 1.f);
    return __builtin_copysignf(r, x);
}

// async global->LDS, 16B/lane. LDS dest semantics: wave-uniform base + lane*16.
static __device__ __forceinline__ void stage16(const void* g, void* ldsBase, int lane) {
#if __has_builtin(__builtin_amdgcn_global_load_lds)
    __builtin_amdgcn_global_load_lds(
        (const __attribute__((address_space(1))) unsigned int*)(uintptr_t)g,
        (__attribute__((address_space(3))) unsigned int*)(unsigned int)(uintptr_t)ldsBase,
        16, 0, 0);
#else
    *(uint4*)((char*)ldsBase + lane * 16) = *(const uint4*)g;
#endif
}

// ---- pack x (fp32) -> Ain0[b][5376]: cols [1232,5328)=x genes, [5328,5376)=0
__global__ __launch_bounds__(256) void pack_ain0(const float* __restrict__ x,
                                                 unsigned short* __restrict__ ain0) {
    const int GPR = 518;  // 16B granules per row
    int i = blockIdx.x * 256 + threadIdx.x;
    if (i >= BDIM * GPR) return;
    int b = i / GPR, g = i % GPR;
    unsigned short* dst = ain0 + (size_t)b * 5376 + 1232 + g * 8;
    if (g < 512) {
        const float* xp = x + (size_t)b * 4096 + g * 8;
        float4 lo = *(const float4*)xp, hi = *(const float4*)(xp + 4);
        union { unsigned short u[8]; uint4 v; } t;
        t.u[0] = f2bf(lo.x); t.u[1] = f2bf(lo.y); t.u[2] = f2bf(lo.z); t.u[3] = f2bf(lo.w);
        t.u[4] = f2bf(hi.x); t.u[5] = f2bf(hi.y); t.u[6] = f2bf(hi.z); t.u[7] = f2bf(hi.w);
        *(uint4*)dst = t.v;
    } else {
        *(uint4*)dst = make_uint4(0u, 0u, 0u, 0u);
    }
}

// ---- pack x -> Ain1[b][t*1344 + 308 .. ]: genes at [308,1332), zeros [1332,1344)
__global__ __launch_bounds__(256) void pack_ain1(const float* __restrict__ x,
                                                 unsigned short* __restrict__ ain1) {
    const int UPT = 259;  // 4-elem units per term
    int i = blockIdx.x * 256 + threadIdx.x;
    if (i >= BDIM * 4 * UPT) return;
    int b = i / (4 * UPT), rem = i % (4 * UPT), t = rem / UPT, u = rem % UPT;
    unsigned short* dst = ain1 + (size_t)b * 5376 + t * 1344 + 308 + u * 4;
    if (u < 256) {
        float4 v = *(const float4*)(x + (size_t)b * 4096 + t * 1024 + u * 4);
        union { unsigned short s[4]; uint2 v; } p;
        p.s[0] = f2bf(v.x); p.s[1] = f2bf(v.y); p.s[2] = f2bf(v.z); p.s[3] = f2bf(v.w);
        *(uint2*)dst = p.v;
    } else {
        *(uint2*)dst = make_uint2(0u, 0u);
    }
}

// ---- W[t][I][O] fp32 -> WbT[t][Npad][Kpad] bf16 (rows o>=O and k>=I zeroed) ----
__global__ __launch_bounds__(256) void cvt_w(const float* __restrict__ W,
                                             unsigned short* __restrict__ WbT,
                                             int I, int O, int Npad, int Kpad) {
    __shared__ unsigned short tile[32][33];
    const int t = blockIdx.z;
    const int i0 = blockIdx.x * 32, o0 = blockIdx.y * 32;
    const int c = threadIdx.x & 31, r0 = threadIdx.x >> 5;
    const float* Wt = W + (size_t)t * I * O;
    #pragma unroll
    for (int rr = 0; rr < 4; rr++) {
        int i = i0 + r0 + rr * 8, o = o0 + c;
        float v = (i < I && o < O) ? Wt[(size_t)i * O + o] : 0.f;
        tile[r0 + rr * 8][c] = f2bf(v);
    }
    __syncthreads();
    unsigned short* dst = WbT + (size_t)t * Npad * Kpad;
    #pragma unroll
    for (int rr = 0; rr < 4; rr++) {
        int o = o0 + r0 + rr * 8, k = i0 + c;
        if (o < Npad) dst[(size_t)o * Kpad + k] = tile[c][r0 + rr * 8];
    }
}

// ---- small-stage GEMM (s4/s3/s2): VGPR staging, bf16 act + fp32 x inline cvt ----
template <int BN, int BK>
__global__ __launch_bounds__(256) void gemm_small(
    const unsigned short* __restrict__ actb,  // [B][T*C] bf16 (null if C==0)
    const float* __restrict__ x,              // [B][4096] fp32
    const unsigned short* __restrict__ WbT,   // [T][O][Kpad] bf16
    const float* __restrict__ bias,
    unsigned short* __restrict__ h,           // [B][hstride]
    int T, int I, int O, int C, int Gs, int Kpad, int hstride)
{
    const int t  = blockIdx.z;
    const int b0 = blockIdx.y * 64;
    const int o0 = blockIdx.x * BN;
    const int tid = threadIdx.x;
    const int lane = tid & 63;
    const int w = tid >> 6;
    const int l15 = lane & 15;
    const int quad = lane >> 4;

    constexpr int NF = BN / 32;
    const int wm = (w & 1) * 32;
    const int wn = (w >> 1) * (BN / 2);

    __shared__ __align__(16) unsigned short As[64][BK + 8];
    __shared__ __align__(16) unsigned short Bs[BN][BK + 8];

    float4v acc[2][NF];
    #pragma unroll
    for (int a = 0; a < 2; a++)
        #pragma unroll
        for (int b = 0; b < NF; b++)
            acc[a][b] = (float4v){0.f, 0.f, 0.f, 0.f};

    constexpr int GR = BK / 8;
    constexpr int AG = 64 * GR;
    constexpr int BG = BN * GR;
    const size_t actRow = (size_t)T * C;

    for (int k0 = 0; k0 < Kpad; k0 += BK) {
        #pragma unroll
        for (int g = tid; g < AG; g += 256) {
            const int r = g / GR, c8 = g % GR;
            const int k = k0 + c8 * 8;
            const int b = b0 + r;
            uint4 v;
            if (k + 8 <= C) {             // act region (granule-aligned for s3/s2)
                v = *(const uint4*)(actb + (size_t)b * actRow + (size_t)t * C + k);
            } else if (k >= I) {
                v = make_uint4(0u, 0u, 0u, 0u);
            } else {                      // gene region, fp32 -> bf16
                const float* xp = x + (size_t)b * 4096 + (size_t)t * Gs + (k - C);
                float4 lo = *(const float4*)xp, hi = *(const float4*)(xp + 4);
                union { unsigned short u[8]; uint4 v; } tmp;
                tmp.u[0] = f2bf(lo.x); tmp.u[1] = f2bf(lo.y); tmp.u[2] = f2bf(lo.z); tmp.u[3] = f2bf(lo.w);
                tmp.u[4] = f2bf(hi.x); tmp.u[5] = f2bf(hi.y); tmp.u[6] = f2bf(hi.z); tmp.u[7] = f2bf(hi.w);
                v = tmp.v;
            }
            *(uint4*)&As[r][c8 * 8] = v;
        }
        #pragma unroll
        for (int g = tid; g < BG; g += 256) {
            const int n = g / GR, c8 = g % GR;
            const int o = o0 + n;
            uint4 v = make_uint4(0u, 0u, 0u, 0u);
            if (o < O)
                v = *(const uint4*)(WbT + ((size_t)t * O + o) * Kpad + k0 + c8 * 8);
            *(uint4*)&Bs[n][c8 * 8] = v;
        }
        __syncthreads();
        #pragma unroll
        for (int ks = 0; ks < BK / 32; ks++) {
            const int koff = ks * 32 + quad * 8;
            short8 a0 = *(const short8*)&As[wm + l15][koff];
            short8 a1 = *(const short8*)&As[wm + 16 + l15][koff];
            #pragma unroll
            for (int fn = 0; fn < NF; fn++) {
                short8 bf = *(const short8*)&Bs[wn + fn * 16 + l15][koff];
                acc[0][fn] = __builtin_amdgcn_mfma_f32_16x16x32_bf16(a0, bf, acc[0][fn], 0, 0, 0);
                acc[1][fn] = __builtin_amdgcn_mfma_f32_16x16x32_bf16(a1, bf, acc[1][fn], 0, 0, 0);
            }
        }
        __syncthreads();
    }

    #pragma unroll
    for (int fm = 0; fm < 2; fm++)
        #pragma unroll
        for (int fn = 0; fn < NF; fn++)
            #pragma unroll
            for (int r = 0; r < 4; r++) {
                int m = wm + fm * 16 + quad * 4 + r;
                int o = o0 + wn + fn * 16 + l15;
                if (o < O) {
                    float v = acc[fm][fn][r] + bias[t * O + o];
                    h[(size_t)(b0 + m) * hstride + (size_t)t * O + o] = f2bf(v);
                }
            }
}

// ---- big-stage GEMM (s1/s0): 128-row tile, BK=32, global_load_lds, split-K ----
// LDS granule layout: pos within row = kg ^ ((row>>1)&3)  => <=2-way bank alias.
template <int BN>
__global__ __launch_bounds__(256) void gemm_split(
    const unsigned short* __restrict__ A,     // [2048][aStride] bf16 (zero-padded)
    const unsigned short* __restrict__ WbT,   // [T][Npad][Kpad] bf16 (zero-padded)
    float* __restrict__ partial,              // [KS][2048][TNpad]
    int aStride, int tStride, int Kpad, int Npad, int KS, int TNpad)
{
    const int tid = threadIdx.x;
    const int lane = tid & 63, w = tid >> 6;
    const int l15 = lane & 15, quad = lane >> 4;
    const int n0 = blockIdx.x * BN;
    const int b0 = blockIdx.y * 128;
    const int ksIdx = blockIdx.z % KS;
    const int t = blockIdx.z / KS;

    __shared__ __align__(16) unsigned short As[128 * 32];
    __shared__ __align__(16) unsigned short Bs[BN * 32];

    const int S = Kpad >> 5;            // total 32-wide K steps
    const int qb = S / KS, rb = S % KS;
    const int beg = ksIdx * qb + (ksIdx < rb ? ksIdx : rb);
    const int cnt = qb + (ksIdx < rb ? 1 : 0);

    constexpr int NF = BN / 32;
    const int wm = (w & 1) * 64;
    const int wn = (w >> 1) * (BN / 2);

    float4v acc[4][NF];
    #pragma unroll
    for (int a = 0; a < 4; a++)
        #pragma unroll
        for (int b = 0; b < NF; b++)
            acc[a][b] = (float4v){0.f, 0.f, 0.f, 0.f};

    // staging sources (per-lane) + LDS bases (wave-uniform)
    const int GA0 = (w * 2) * 64 + lane, GA1 = GA0 + 64;
    const int rA0 = GA0 >> 2, rA1 = GA1 >> 2;
    const int kgA0 = (GA0 & 3) ^ ((rA0 >> 1) & 3);
    const int kgA1 = (GA1 & 3) ^ ((rA1 >> 1) & 3);
    const unsigned short* aS0 = A + (size_t)(b0 + rA0) * aStride + (size_t)t * tStride + kgA0 * 8;
    const unsigned short* aS1 = A + (size_t)(b0 + rA1) * aStride + (size_t)t * tStride + kgA1 * 8;
    unsigned short* lA0 = &As[(w * 2 + 0) * 512];
    unsigned short* lA1 = &As[(w * 2 + 1) * 512];

    const unsigned short* bS0;
    const unsigned short* bS1 = nullptr;
    unsigned short* lB0;
    unsigned short* lB1 = nullptr;
    if (BN == 64) {
        const int G = w * 64 + lane;
        const int r = G >> 2, kg = (G & 3) ^ ((r >> 1) & 3);
        bS0 = WbT + ((size_t)t * Npad + n0 + r) * Kpad + kg * 8;
        lB0 = &Bs[w * 512];
    } else {
        const int G0 = (w * 2) * 64 + lane, G1 = G0 + 64;
        const int r0 = G0 >> 2, r1 = G1 >> 2;
        bS0 = WbT + ((size_t)t * Npad + n0 + r0) * Kpad + ((G0 & 3) ^ ((r0 >> 1) & 3)) * 8;
        bS1 = WbT + ((size_t)t * Npad + n0 + r1) * Kpad + ((G1 & 3) ^ ((r1 >> 1) & 3)) * 8;
        lB0 = &Bs[(w * 2 + 0) * 512];
        lB1 = &Bs[(w * 2 + 1) * 512];
    }

    for (int s = 0; s < cnt; s++) {
        const int k0 = (beg + s) << 5;
        __syncthreads();                       // prev MFMA reads done before overwrite
        stage16(aS0 + k0, lA0, lane);
        stage16(aS1 + k0, lA1, lane);
        stage16(bS0 + k0, lB0, lane);
        if (BN == 128) stage16(bS1 + k0, lB1, lane);
        __syncthreads();                       // drains vmcnt -> LDS ready

        short8 af[4];
        #pragma unroll
        for (int fm = 0; fm < 4; fm++) {
            int m = wm + fm * 16 + l15;
            int pos = quad ^ ((m >> 1) & 3);
            af[fm] = *(const short8*)&As[(m * 4 + pos) * 8];
        }
        short8 bfr[NF];
        #pragma unroll
        for (int fn = 0; fn < NF; fn++) {
            int n = wn + fn * 16 + l15;
            int pos = quad ^ ((n >> 1) & 3);
            bfr[fn] = *(const short8*)&Bs[(n * 4 + pos) * 8];
        }
        #pragma unroll
        for (int fm = 0; fm < 4; fm++)
            #pragma unroll
            for (int fn = 0; fn < NF; fn++)
                acc[fm][fn] = __builtin_amdgcn_mfma_f32_16x16x32_bf16(af[fm], bfr[fn], acc[fm][fn], 0, 0, 0);
    }

    const size_t pBase = ((size_t)ksIdx * BDIM + b0) * TNpad + (size_t)t * Npad + n0;
    #pragma unroll
    for (int fm = 0; fm < 4; fm++)
        #pragma unroll
        for (int r = 0; r < 4; r++) {
            const int m = wm + fm * 16 + quad * 4 + r;
            float* prow = partial + pBase + (size_t)m * TNpad + wn;
            #pragma unroll
            for (int fn = 0; fn < NF; fn++)
                prow[fn * 16 + l15] = acc[fm][fn][r];
        }
}

// ---- split-K reduce + bias + bf16 store ----
__global__ __launch_bounds__(256) void reduce_split(
    const float* __restrict__ partial, const float* __restrict__ bias,
    unsigned short* __restrict__ h, int T, int O, int Npad, int KS, int hstride)
{
    const long long total = (long long)BDIM * T * O;
    long long i = (long long)blockIdx.x * 256 + threadIdx.x;
    if (i >= total) return;
    int b = (int)(i / (T * O));
    int col = (int)(i % (T * O));
    int t = col / O, o = col % O;
    const size_t TNpad = (size_t)T * Npad;
    const float* p = partial + (size_t)b * TNpad + (size_t)t * Npad + o;
    float s = 0.f;
    for (int ks = 0; ks < KS; ks++) s += p[(size_t)ks * BDIM * TNpad];
    h[(size_t)b * hstride + col] = f2bf(s + bias[col]);
}

// ---- BN batch sums: chunked atomic reduce over B ----
__global__ __launch_bounds__(256) void bn_stats(const unsigned short* __restrict__ h,
                                                float* __restrict__ acc, int TO, int hstride) {
    int col = blockIdx.x * 256 + threadIdx.x;
    if (col >= TO) return;
    const unsigned short* p = h + (size_t)blockIdx.y * 128 * hstride + col;
    float s = 0.f, s2 = 0.f;
    #pragma unroll 4
    for (int b = 0; b < 128; b++) {
        float v = bf2f(p[(size_t)b * hstride]);
        s += v; s2 += v * v;
    }
    atomicAdd(&acc[col], s);
    atomicAdd(&acc[TO + col], s2);
}

// ---- sums -> per-col scale/shift (in place): scale=rsig*g, shift=bb-mu*scale ----
__global__ __launch_bounds__(256) void bn_scale(float* __restrict__ acc,
                                                const float* __restrict__ g,
                                                const float* __restrict__ bb, int TO) {
    int col = blockIdx.x * 256 + threadIdx.x;
    if (col >= TO) return;
    float mu = acc[col] * (1.f / BDIM);
    float var = acc[TO + col] * (1.f / BDIM) - mu * mu;  // biased, matches jnp.var
    float scale = rsqrtf(var + 1e-5f) * g[col];
    acc[col] = scale;
    acc[TO + col] = bb[col] - mu * scale;
}

// ---- vectorized BN+tanh+head for O=20 in-place stages (s4/s3) ----
// Block handles RPB rows; thread j-th granule = 4 contiguous cols (uint2).
// rowGran = hstride/4; granules/term = O/4 = 5; RPB*rowGran == 256*GPT.
template <int GPT>
__global__ __launch_bounds__(256) void bn_tanh_head_vec(
    unsigned short* hact,                    // in: h, out: act (in place)
    const float* __restrict__ ss,            // [hstride]=scale, [hstride..)=shift
    const float* __restrict__ hw, const float* __restrict__ hb,
    float* __restrict__ out,
    int T, int rowGran, int RPB, int hstride, int head_off)
{
    __shared__ float headAcc[256];
    const int tid = threadIdx.x;
    headAcc[tid] = 0.f;
    __syncthreads();
    const int b0 = blockIdx.x * RPB;

    uint2 hv[GPT];
    #pragma unroll
    for (int j = 0; j < GPT; j++) {
        int G = tid + j * 256;
        int r = G / rowGran, gg = G % rowGran;
        hv[j] = *(const uint2*)(hact + (size_t)(b0 + r) * hstride + gg * 4);
    }
    #pragma unroll
    for (int j = 0; j < GPT; j++) {
        int G = tid + j * 256;
        int r = G / rowGran, gg = G % rowGran;
        int c = gg * 4;
        float4 sc = *(const float4*)(ss + c);
        float4 sh = *(const float4*)(ss + hstride + c);
        float4 w4 = *(const float4*)(hw + c);
        union { unsigned short u[4]; uint2 v; } iv, ov;
        iv.v = hv[j];
        float a0 = fast_tanh(bf2f(iv.u[0]) * sc.x + sh.x);
        float a1 = fast_tanh(bf2f(iv.u[1]) * sc.y + sh.y);
        float a2 = fast_tanh(bf2f(iv.u[2]) * sc.z + sh.z);
        float a3 = fast_tanh(bf2f(iv.u[3]) * sc.w + sh.w);
        ov.u[0] = f2bf(a0); ov.u[1] = f2bf(a1); ov.u[2] = f2bf(a2); ov.u[3] = f2bf(a3);
        *(uint2*)(hact + (size_t)(b0 + r) * hstride + c) = ov.v;
        float partial = a0 * w4.x + a1 * w4.y + a2 * w4.z + a3 * w4.w;
        int t = gg / 5;   // 5 granules per term (O=20)
        atomicAdd(&headAcc[r * T + t], partial);
    }
    __syncthreads();
    if (tid < RPB * T) {
        int r = tid / T, t = tid % T;
        out[(size_t)(b0 + r) * OUTW + head_off + t] = headAcc[tid] + hb[t];
    }
}

// ---- BN(final fused) + tanh + strided act store + head — WAVE variant ----
__global__ __launch_bounds__(256) void bn_tanh_head(
    const unsigned short* __restrict__ h, const float* __restrict__ stats,
    const float* __restrict__ g, const float* __restrict__ bb,
    const float* __restrict__ hw, const float* __restrict__ hb,
    unsigned short* __restrict__ actOut, float* __restrict__ out,
    int T, int O, int hstride, int aRow, int GT, int GS, int head_off)
{
    int wid  = (blockIdx.x * 256 + threadIdx.x) >> 6;
    int lane = threadIdx.x & 63;
    int b = wid / T;
    int t = wid % T;
    const int TO = T * O;
    const size_t hbase = (size_t)b * hstride + (size_t)t * O;
    const size_t abase = (size_t)b * aRow + (size_t)(t / GT) * GS + (size_t)(t % GT) * O;
    float hsum = 0.f;
    for (int o = lane; o < O; o += 64) {
        int col = t * O + o;
        float mu = stats[col] * (1.f / BDIM);
        float var = stats[TO + col] * (1.f / BDIM) - mu * mu;
        float rsig = rsqrtf(var + 1e-5f);
        float a = fast_tanh((bf2f(h[hbase + o]) - mu) * rsig * g[col] + bb[col]);
        actOut[abase + o] = f2bf(a);
        hsum += a * hw[col];
    }
    #pragma unroll
    for (int off = 32; off > 0; off >>= 1) hsum += __shfl_down(hsum, off, 64);
    if (lane == 0) out[(size_t)b * OUTW + head_off + t] = hsum + hb[t];
}

extern "C" void kernel_launch(void* const* d_in, const int* in_sizes, int n_in,
                              void* d_out, int out_size, void* d_ws, size_t ws_size,
                              hipStream_t stream)
{
    const float* x = (const float*)d_in[0];
    float* out = (float*)d_out;
    char* ws = (char*)d_ws;

    // ws layout (bytes); total ~89.1 MB
    unsigned short* wbt  = (unsigned short*)(ws);              // 13,762,560 (s0 WbT max)
    unsigned short* ain0 = (unsigned short*)(ws + 13762560);   // 22,020,096 (2048x5376)
    unsigned short* bufA = (unsigned short*)(ws + 35782656);   // 20,971,520 (h4/act4 2048x5120)
    unsigned short* bufB = (unsigned short*)(ws + 56754176);   //  5,242,880 (h3/act3 2048x1280)
    unsigned short* ain1 = (unsigned short*)(ws + 61997056);   // 22,020,096 (2048x5376)
    unsigned short* bufC = (unsigned short*)(ws + 84017152);   //  5,046,272 (h2/h1/h0 2048x1232)
    float*          stats= (float*)(ws + 89063424);            //     40,960
    // split-K partials overlay bufA.. (dead by use time): s1 20.9MB, s0 41.9MB
    float* partial = (float*)(ws + 35782656);

    pack_ain0<<<(BDIM * 518 + 255) / 256, 256, 0, stream>>>(x, ain0);
    pack_ain1<<<(BDIM * 4 * 259 + 255) / 256, 256, 0, stream>>>(x, ain1);

    const float* W4 = (const float*)d_in[1];  const float* b4 = (const float*)d_in[2];
    const float* g4 = (const float*)d_in[3];  const float* bb4 = (const float*)d_in[4];
    const float* hw4 = (const float*)d_in[5]; const float* hb4 = (const float*)d_in[6];
    const float* W3 = (const float*)d_in[7];  const float* b3 = (const float*)d_in[8];
    const float* g3 = (const float*)d_in[9];  const float* bb3 = (const float*)d_in[10];
    const float* hw3 = (const float*)d_in[11]; const float* hb3 = (const float*)d_in[12];
    const float* W2 = (const float*)d_in[13]; const float* b2 = (const float*)d_in[14];
    const float* g2 = (const float*)d_in[15]; const float* bb2 = (const float*)d_in[16];
    const float* hw2 = (const float*)d_in[17]; const float* hb2 = (const float*)d_in[18];
    const float* W1 = (const float*)d_in[19]; const float* b1 = (const float*)d_in[20];
    const float* g1 = (const float*)d_in[21]; const float* bb1 = (const float*)d_in[22];
    const float* hw1 = (const float*)d_in[23]; const float* hb1 = (const float*)d_in[24];
    const float* W0 = (const float*)d_in[25]; const float* b0_ = (const float*)d_in[26];
    const float* g0 = (const float*)d_in[27]; const float* bb0 = (const float*)d_in[28];
    const float* hw0 = (const float*)d_in[29]; const float* hb0 = (const float*)d_in[30];

    // ---------------- s4: T=256 I=16 O=20 C=0 Gs=16 Kpad=32 ----------------
    cvt_w<<<dim3(1, 1, 256), 256, 0, stream>>>(W4, wbt, 16, 20, 20, 32);
    gemm_small<32, 32><<<dim3(1, 32, 256), 256, 0, stream>>>(nullptr, x, wbt, b4, bufA,
                                                             256, 16, 20, 0, 16, 32, 5120);
    hipMemsetAsync(stats, 0, 2 * 5120 * sizeof(float), stream);
    bn_stats<<<dim3(20, 16), 256, 0, stream>>>(bufA, stats, 5120, 5120);
    bn_scale<<<20, 256, 0, stream>>>(stats, g4, bb4, 5120);
    // rowGran=1280, RPB=1, GPT=5, grid=2048
    bn_tanh_head_vec<5><<<BDIM, 256, 0, stream>>>(bufA, stats, hw4, hb4, out,
                                                  256, 1280, 1, 5120, 0);

    // ---------------- s3: T=64 I=144 O=20 C=80 Gs=64 Kpad=192 ----------------
    cvt_w<<<dim3(6, 1, 64), 256, 0, stream>>>(W3, wbt, 144, 20, 20, 192);
    gemm_small<32, 64><<<dim3(1, 32, 64), 256, 0, stream>>>(bufA, x, wbt, b3, bufB,
                                                            64, 144, 20, 80, 64, 192, 1280);
    hipMemsetAsync(stats, 0, 2 * 1280 * sizeof(float), stream);
    bn_stats<<<dim3(5, 16), 256, 0, stream>>>(bufB, stats, 1280, 1280);
    bn_scale<<<5, 256, 0, stream>>>(stats, g3, bb3, 1280);
    // rowGran=320, RPB=4, GPT=5, grid=512
    bn_tanh_head_vec<5><<<BDIM / 4, 256, 0, stream>>>(bufB, stats, hw3, hb3, out,
                                                      64, 320, 4, 1280, 256);

    // ---------------- s2: T=16 I=336 O=77 C=80 Gs=256 Kpad=384 ----------------
    cvt_w<<<dim3(12, 3, 16), 256, 0, stream>>>(W2, wbt, 336, 77, 77, 384);
    gemm_small<64, 64><<<dim3(2, 32, 16), 256, 0, stream>>>(bufB, x, wbt, b2, bufC,
                                                            16, 336, 77, 80, 256, 384, 1232);
    hipMemsetAsync(stats, 0, 2 * 1232 * sizeof(float), stream);
    bn_stats<<<dim3(5, 16), 256, 0, stream>>>(bufC, stats, 1232, 1232);
    // act2 -> Ain1 strided: col = (t/4)*1344 + (t%4)*77 + o
    bn_tanh_head<<<BDIM * 16 / 4, 256, 0, stream>>>(bufC, stats, g2, bb2, hw2, hb2,
                                                    ain1, out, 16, 77, 1232, 5376, 4, 1344, 320);

    // ---------------- s1: T=4 I=1332 O=308 Kpad=1344 Npad=320 KS=2 ----------------
    cvt_w<<<dim3(42, 10, 4), 256, 0, stream>>>(W1, wbt, 1332, 308, 320, 1344);
    gemm_split<64><<<dim3(5, 16, 8), 256, 0, stream>>>(ain1, wbt, partial,
                                                       5376, 1344, 1344, 320, 2, 1280);
    reduce_split<<<(BDIM * 4 * 308 + 255) / 256, 256, 0, stream>>>(partial, b1, bufC,
                                                                   4, 308, 320, 2, 1232);
    hipMemsetAsync(stats, 0, 2 * 1232 * sizeof(float), stream);
    bn_stats<<<dim3(5, 16), 256, 0, stream>>>(bufC, stats, 1232, 1232);
    // act1 -> Ain0 cols [0,1232): col = t*308 + o
    bn_tanh_head<<<BDIM * 4 / 4, 256, 0, stream>>>(bufC, stats, g1, bb1, hw1, hb1,
                                                   ain0, out, 4, 308, 1232, 5376, 4, 0, 336);

    // ---------------- s0: T=1 I=5328 O=1229 Kpad=5376 Npad=1280 KS=4 ----------------
    cvt_w<<<dim3(168, 40, 1), 256, 0, stream>>>(W0, wbt, 5328, 1229, 1280, 5376);
    gemm_split<128><<<dim3(10, 16, 4), 256, 0, stream>>>(ain0, wbt, partial,
                                                         5376, 0, 5376, 1280, 4, 1280);
    reduce_split<<<(BDIM * 1229 + 255) / 256, 256, 0, stream>>>(partial, b0_, bufC,
                                                                1, 1229, 1280, 4, 1232);
    hipMemsetAsync(stats, 0, 2 * 1229 * sizeof(float), stream);
    bn_stats<<<dim3(5, 16), 256, 0, stream>>>(bufC, stats, 1229, 1232);
    bn_tanh_head<<<BDIM / 4, 256, 0, stream>>>(bufC, stats, g0, bb0, hw0, hb0,
                                               bufC, out, 1, 1229, 1232, 1232, 1, 0, 340);
}